// Round 12
// baseline (154.856 us; speedup 1.0000x reference)
//
#include <hip/hip_runtime.h>
#include <math.h>

#define BB 8
#define TT 16384
#define DD 128
#define DH 64
#define FCAP 32768
#define FMARGIN 0.05f

typedef _Float16 half8 __attribute__((ext_vector_type(8)));
typedef float f32x4 __attribute__((ext_vector_type(4)));

union H8 { half8 h; uint4 q; ushort us[8]; };

static __device__ __forceinline__ float4 ld4(const float* p) { return *(const float4*)p; }

static __device__ __forceinline__ uint pk2(float a, float b) {
    union { _Float16 f; ushort u; } A, B;
    A.f = (_Float16)a; B.f = (_Float16)b;
    return (uint)A.u | ((uint)B.u << 16);
}
static __device__ __forceinline__ ushort f2h(float a) {
    union { _Float16 f; ushort u; } A; A.f = (_Float16)a; return A.u;
}
static __device__ __forceinline__ float h2f(ushort u) {
    union { ushort u; _Float16 f; } A; A.u = u; return (float)A.f;
}

// split 8 fp32 -> fp16 hi + fp16 lo (x = hi + lo exact to ~2^-22)
static __device__ __forceinline__ void split8h(const float4 v0, const float4 v1,
                                               half8* xh, half8* xl)
{
    float f[8] = {v0.x, v0.y, v0.z, v0.w, v1.x, v1.y, v1.z, v1.w};
    half8 h, l;
    #pragma unroll
    for (int j = 0; j < 8; ++j) {
        _Float16 hv = (_Float16)f[j];
        h[j] = hv;
        l[j] = (_Float16)(f[j] - (float)hv);
    }
    *xh = h; *xl = l;
}

// ---------------------------------------------------------------------------
// Kernel W-prep: weights fp32 -> fp16 MFMA B-fragment layout (single fp16).
// ---------------------------------------------------------------------------
__global__ __launch_bounds__(64) void k_wprep(
    const float* __restrict__ Wa1, const float* __restrict__ Wa2,
    const float* __restrict__ Wd, const float* __restrict__ Wk,
    const float* __restrict__ Wq, ushort* __restrict__ wfm,
    ushort* __restrict__ wfb, int* __restrict__ fcnt)
{
    const int l  = threadIdx.x;
    const int nt = blockIdx.x & 7;
    const int kb = blockIdx.x >> 3;
    const int ly = blockIdx.y;
    if (ly == 0 && blockIdx.x == 0 && l == 0) *fcnt = 0;
    const int n  = nt * 16 + (l & 15);
    const int k0 = kb * 32 + (l >> 4) * 8;
    H8 v;
    if (ly < 3) {
        const float* W = (ly == 0) ? Wa1 : (ly == 1) ? Wa2 : Wd;
        #pragma unroll
        for (int e = 0; e < 8; ++e) v.h[e] = (_Float16)W[(k0 + e) * DD + n];
        *(uint4*)(wfm + (size_t)(((ly * 8 + nt) * 4 + kb) * 64 + l) * 8) = v.q;
    } else {
        #pragma unroll
        for (int e = 0; e < 8; ++e) {
            float w = (n < 64) ? Wk[(k0 + e) * DH + n] : Wq[(k0 + e) * DH + n - 64];
            v.h[e] = (_Float16)w;
        }
        *(uint4*)(wfb + (size_t)((nt * 4 + kb) * 64 + l) * 8) = v.q;
    }
}

// ---------------------------------------------------------------------------
// Kernel 1: binding logits via fp16 MFMA, 2-product. (unchanged from r8)
// ---------------------------------------------------------------------------
__global__ __launch_bounds__(256, 2) void k_bind(
    const float* __restrict__ x, const ushort* __restrict__ wfb,
    const float* __restrict__ bk, const float* __restrict__ bq,
    int* __restrict__ cstart, int* __restrict__ flist, int* __restrict__ fcnt)
{
    __shared__ uint4 Bs4[2048];
    __shared__ float bnd[4][64];
    const int b    = blockIdx.y;
    const int tb   = blockIdx.x * 64;
    const int tid  = threadIdx.x;
    const int wv   = tid >> 6;
    const int l    = tid & 63;
    const int lo16 = l & 15;
    const int g    = l >> 4;

    {
        const uint4* wsrc = (const uint4*)wfb;
        #pragma unroll
        for (int j = 0; j < 8; ++j) { int idx = tid + j * 256; Bs4[idx] = wsrc[idx]; }
    }

    const float* xrow = x + ((size_t)b * TT + tb + wv * 16 + lo16) * DD;
    half8 xh[4], xl[4];
    #pragma unroll
    for (int kb = 0; kb < 4; ++kb) {
        float4 v0 = ld4(xrow + kb * 32 + g * 8);
        float4 v1 = ld4(xrow + kb * 32 + g * 8 + 4);
        split8h(v0, v1, &xh[kb], &xl[kb]);
    }
    int r64 = tb + 64; if (r64 > TT - 1) r64 = TT - 1;
    const float* xq = x + ((size_t)b * TT + r64) * DD;
    half8 qh[4], ql[4];
    H8 z; z.q.x = z.q.y = z.q.z = z.q.w = 0u;
    #pragma unroll
    for (int kb = 0; kb < 4; ++kb) {
        qh[kb] = z.h; ql[kb] = z.h;
        if (lo16 == 0) {
            float4 v0 = ld4(xq + kb * 32 + g * 8);
            float4 v1 = ld4(xq + kb * 32 + g * 8 + 4);
            split8h(v0, v1, &qh[kb], &ql[kb]);
        }
    }

    f32x4 acc[8];
    #pragma unroll
    for (int nt = 0; nt < 8; ++nt) {
        int col = nt * 16 + lo16;
        float bias = (col < 64) ? bk[col] : bq[col - 64];
        acc[nt] = (f32x4){bias, bias, bias, bias};
    }
    f32x4 acc4;
    {
        float bias = bq[wv * 16 + lo16];
        acc4 = (f32x4){bias, bias, bias, bias};
    }

    __syncthreads();
    const ushort* Bs = (const ushort*)Bs4;
    const ushort* Bs_halo = Bs + (size_t)((4 + wv) * 4 * 64 + l) * 8;
    #pragma unroll
    for (int kb = 0; kb < 4; ++kb) {
        half8 bh[8];
        #pragma unroll
        for (int nt = 0; nt < 8; ++nt)
            bh[nt] = *(const half8*)(Bs + (size_t)((nt * 4 + kb) * 64 + l) * 8);
        #pragma unroll
        for (int nt = 0; nt < 8; ++nt) {
            acc[nt] = __builtin_amdgcn_mfma_f32_16x16x32_f16(xh[kb], bh[nt], acc[nt], 0, 0, 0);
            acc[nt] = __builtin_amdgcn_mfma_f32_16x16x32_f16(xl[kb], bh[nt], acc[nt], 0, 0, 0);
        }
        half8 bh4 = *(const half8*)(Bs_halo + (size_t)kb * 64 * 8);
        acc4 = __builtin_amdgcn_mfma_f32_16x16x32_f16(qh[kb], bh4, acc4, 0, 0, 0);
        acc4 = __builtin_amdgcn_mfma_f32_16x16x32_f16(ql[kb], bh4, acc4, 0, 0, 0);
    }

    if (l < 16) {
        if (wv > 0) {
            #pragma unroll
            for (int nt = 0; nt < 4; ++nt) bnd[wv - 1][nt * 16 + lo16] = acc[4 + nt][0];
        }
        bnd[3][wv * 16 + lo16] = acc4[0];
    }
    __syncthreads();

    float qn3[4];
    #pragma unroll
    for (int nt = 0; nt < 4; ++nt) qn3[nt] = __shfl_down(acc[4 + nt][0], 16);
    if (g == 3) {
        #pragma unroll
        for (int nt = 0; nt < 4; ++nt) qn3[nt] = bnd[wv][nt * 16 + lo16];
    }
    float s[4];
    #pragma unroll
    for (int i = 0; i < 3; ++i) {
        float t = 0.f;
        #pragma unroll
        for (int nt = 0; nt < 4; ++nt) t += acc[nt][i] * acc[4 + nt][i + 1];
        s[i] = t;
    }
    {
        float t = 0.f;
        #pragma unroll
        for (int nt = 0; nt < 4; ++nt) t += acc[nt][3] * qn3[nt];
        s[3] = t;
    }
    #pragma unroll
    for (int i = 0; i < 4; ++i) {
        #pragma unroll
        for (int m = 1; m < 16; m <<= 1) s[i] += __shfl_xor(s[i], m);
    }
    if (lo16 == 0) {
        #pragma unroll
        for (int i = 0; i < 4; ++i) {
            int t = tb + wv * 16 + g * 4 + i;
            if (t <= TT - 2) {
                cstart[b * TT + t + 1] = (s[i] > 0.f) ? 0 : 1;
                if (fabsf(s[i]) < FMARGIN) {
                    int pos = atomicAdd(fcnt, 1);
                    if (pos < FCAP) flist[pos] = b * TT + t;
                }
            }
        }
    }
    if (blockIdx.x == 0 && tid == 0) cstart[b * TT] = 1;
}

// ---------------------------------------------------------------------------
// Kernel 1b: exact fp32 recompute of flagged borderline bind decisions.
// ---------------------------------------------------------------------------
__global__ __launch_bounds__(256) void k_fixup(
    const float* __restrict__ x, const float* __restrict__ Wk, const float* __restrict__ bk,
    const float* __restrict__ Wq, const float* __restrict__ bq,
    const int* __restrict__ flist, const int* __restrict__ fcnt, int* __restrict__ cstart)
{
    const int n    = min(*fcnt, FCAP);
    const int wv   = (blockIdx.x * 256 + threadIdx.x) >> 6;
    const int lane = threadIdx.x & 63;
    const int nwv  = gridDim.x * 4;
    for (int i = wv; i < n; i += nwv) {
        int idx = flist[i];
        int b = idx >> 14;
        int t = idx & (TT - 1);
        const float* xt = x + ((size_t)b * TT + t) * DD;
        float K = bk[lane], Q = bq[lane];
        #pragma unroll 8
        for (int k = 0; k < DD; ++k) {
            K = fmaf(xt[k],      Wk[k * DH + lane], K);
            Q = fmaf(xt[DD + k], Wq[k * DH + lane], Q);
        }
        float p = K * Q;
        #pragma unroll
        for (int m = 1; m < 64; m <<= 1) p += __shfl_xor(p, m);
        if (lane == 0) cstart[b * TT + t + 1] = (p > 0.f) ? 0 : 1;
    }
}

// ---------------------------------------------------------------------------
// Kernel 2: per-batch scan -> seg, chunk-start table, counts. (unchanged)
// ---------------------------------------------------------------------------
__global__ __launch_bounds__(1024) void k_scan(const int* __restrict__ cstart,
    int* __restrict__ seg, int* __restrict__ cs, int* __restrict__ numC)
{
    __shared__ int wsum[16];
    const int b = blockIdx.x, tid = threadIdx.x;
    const int wv = tid >> 6, lane = tid & 63;
    const int base = b * TT + tid * 16;
    int v[16];
    #pragma unroll
    for (int i = 0; i < 4; ++i) {
        int4 q = *(const int4*)(cstart + base + i * 4);
        v[i * 4 + 0] = q.x; v[i * 4 + 1] = q.y; v[i * 4 + 2] = q.z; v[i * 4 + 3] = q.w;
    }
    int s[16]; int run = 0;
    #pragma unroll
    for (int i = 0; i < 16; ++i) { run += v[i]; s[i] = run; }
    int incl = run;
    #pragma unroll
    for (int off = 1; off < 64; off <<= 1) {
        int t = __shfl_up(incl, off);
        if (lane >= off) incl += t;
    }
    if (lane == 63) wsum[wv] = incl;
    __syncthreads();
    if (tid < 16) {
        int w = wsum[tid];
        #pragma unroll
        for (int off = 1; off < 16; off <<= 1) {
            int t = __shfl_up(w, off, 16);
            if (tid >= off) w += t;
        }
        wsum[tid] = w;
    }
    __syncthreads();
    const int excl = (wv ? wsum[wv - 1] : 0) + incl - run;
    #pragma unroll
    for (int i = 0; i < 16; ++i) {
        int sg = excl + s[i] - 1;
        seg[base + i] = sg;
        if (v[i]) cs[b * (TT + 1) + sg] = tid * 16 + i;
    }
    if (tid == 1023) {
        int tot = excl + run;
        numC[b] = tot;
        cs[b * (TT + 1) + tot] = TT;
    }
}

// ---------------------------------------------------------------------------
// k_mlp GEMM: acc[8] = A(fp16 frags in LDS) @ B(fp16 frags in LDS).
// ---------------------------------------------------------------------------
__device__ __forceinline__ void mlp_gemm(f32x4 acc[8], const uint4* Afr4,
    const ushort* Bs, int wv, int l)
{
    half8 af[4];
    #pragma unroll
    for (int kb = 0; kb < 4; ++kb)
        af[kb] = *(const half8*)((const char*)Afr4 + ((wv * 4 + kb) * 64 + l) * 16);
    #pragma unroll
    for (int kb = 0; kb < 4; ++kb) {
        half8 bh[8];
        #pragma unroll
        for (int nt = 0; nt < 8; ++nt)
            bh[nt] = *(const half8*)(Bs + (size_t)((nt * 4 + kb) * 64 + l) * 8);
        #pragma unroll
        for (int nt = 0; nt < 8; ++nt)
            acc[nt] = __builtin_amdgcn_mfma_f32_16x16x32_f16(af[kb], bh[nt], acc[nt], 0, 0, 0);
    }
}

// ---------------------------------------------------------------------------
// Kernel 3: per-chunk MLP via fp16 MFMA. 32 CHUNKS/BLOCK (r12): grid doubles
// to ~2048 active blocks and LDS union shrinks to 40960 B -> 4 blocks/CU
// resident (was 3 at 48KB) -> barrier stalls interleave across blocks.
// Waves 0-1 run the GEMMs/LN (16 rows each, LN stays in-wave); all 4 waves
// do token staging/reduce/B-staging. Gate written fp16 to gate2.
// ---------------------------------------------------------------------------
__global__ __launch_bounds__(256, 2) void k_mlp(
    const float* __restrict__ x, const int* __restrict__ cs,
    const float* __restrict__ ba1, const float* __restrict__ ln_g, const float* __restrict__ ln_b,
    const float* __restrict__ ba2, const float* __restrict__ bd,
    const ushort* __restrict__ wfm, const int* __restrict__ numC, ushort* __restrict__ gate2)
{
    __shared__ union {
        float Tok[64 * 132];                               // 33792 B token tile
        struct { uint4 Afr[512]; uint4 Bs[2048]; } fb;     // 40960 B frags
    } sm;
    const int b  = blockIdx.y;
    const int nC = numC[b];
    const int c0 = blockIdx.x * 32;
    if (c0 >= nC) return;
    const int tid  = threadIdx.x;
    const int wv   = tid >> 6;
    const int l    = tid & 63;
    const int lo16 = l & 15;
    const int g    = l >> 4;
    const ushort* Bs = (const ushort*)sm.fb.Bs;
    const uint4* wsrc = (const uint4*)wfm;

    // pre-issue B layer 0 into registers (hides under phase 1)
    uint4 breg[8];
    #pragma unroll
    for (int j = 0; j < 8; ++j) breg[j] = wsrc[tid + j * 256];

    // ---- phase 1: chunk means (token tiles through LDS, reduce in regs) ----
    const int cbase = b * (TT + 1);
    const int T0 = cs[cbase + c0];
    const int cEnd = (c0 + 32 < nC) ? (c0 + 32) : nC;
    const int T1 = cs[cbase + cEnd];
    int t0r[4], t1r[4];
    #pragma unroll
    for (int ii = 0; ii < 4; ++ii) {
        int r = (tid + ii * 256) >> 5;      // r in [0,32)
        int c = c0 + r;
        t0r[ii] = (c < nC) ? cs[cbase + c] : 0;
        t1r[ii] = (c < nC) ? cs[cbase + c + 1] : 0;
    }
    float4 vals[4];
    #pragma unroll
    for (int ii = 0; ii < 4; ++ii) vals[ii] = make_float4(0.f, 0.f, 0.f, 0.f);

    for (int tt = T0; tt < T1; tt += 64) {
        __syncthreads();
        const int tEnd = (tt + 64 < T1) ? (tt + 64) : T1;
        for (int j = tid; j < (tEnd - tt) * 32; j += 256) {
            int trow = j >> 5, c4 = (j & 31) * 4;
            *(float4*)&sm.Tok[trow * 132 + c4] =
                ld4(x + ((size_t)b * TT + tt + trow) * DD + c4);
        }
        __syncthreads();
        #pragma unroll
        for (int ii = 0; ii < 4; ++ii) {
            int c4 = ((tid + ii * 256) & 31) * 4;
            int lo = (t0r[ii] > tt)   ? t0r[ii] : tt;
            int hi = (t1r[ii] < tEnd) ? t1r[ii] : tEnd;
            for (int t = lo; t < hi; ++t) {
                const float* ap = &sm.Tok[(t - tt) * 132 + c4];
                vals[ii].x += ap[0]; vals[ii].y += ap[1];
                vals[ii].z += ap[2]; vals[ii].w += ap[3];
            }
        }
    }
    __syncthreads();                           // Tok dies; union flips to frags

    // write B0 from regs; divide means; pack fp16 A-frags; pre-issue B1
    #pragma unroll
    for (int j = 0; j < 8; ++j) sm.fb.Bs[tid + j * 256] = breg[j];
    #pragma unroll
    for (int ii = 0; ii < 4; ++ii) {
        int i = tid + ii * 256;
        int r = i >> 5, c4 = (i & 31) * 4;
        float4 sv = make_float4(0.f, 0.f, 0.f, 0.f);
        if (c0 + r < nC) {
            float inv = 1.f / (float)(t1r[ii] - t0r[ii]);
            sv.x = vals[ii].x * inv; sv.y = vals[ii].y * inv;
            sv.z = vals[ii].z * inv; sv.w = vals[ii].w * inv;
        }
        int frag = (r >> 4) * 4 + (c4 >> 5);   // frag in [0,8)
        int lanef = (r & 15) + (((c4 & 31) >> 3) * 16);
        uint2 pk = make_uint2(pk2(sv.x, sv.y), pk2(sv.z, sv.w));
        *(uint2*)((char*)sm.fb.Afr + frag * 1024 + lanef * 16 + (c4 & 7) * 2) = pk;
    }
    #pragma unroll
    for (int j = 0; j < 8; ++j) breg[j] = wsrc[2048 + tid + j * 256];
    __syncthreads();

    // ---- layer 1: h = cm @ Wa1 + ba1; LayerNorm; ReLU (waves 0-1) ----
    f32x4 acc[8];
    float mu_[4], rs_[4], gam[8], bet[8];
    if (wv < 2) {
        #pragma unroll
        for (int nt = 0; nt < 8; ++nt) {
            float bias = ba1[nt * 16 + lo16];
            acc[nt] = (f32x4){bias, bias, bias, bias};
        }
        mlp_gemm(acc, sm.fb.Afr, Bs, wv, l);
        #pragma unroll
        for (int i = 0; i < 4; ++i) {
            float smv = 0.f;
            #pragma unroll
            for (int nt = 0; nt < 8; ++nt) smv += acc[nt][i];
            #pragma unroll
            for (int k = 1; k < 16; k <<= 1) smv += __shfl_xor(smv, k, 16);
            mu_[i] = smv * (1.f / 128.f);
            float vs = 0.f;
            #pragma unroll
            for (int nt = 0; nt < 8; ++nt) { float d = acc[nt][i] - mu_[i]; vs += d * d; }
            #pragma unroll
            for (int k = 1; k < 16; k <<= 1) vs += __shfl_xor(vs, k, 16);
            rs_[i] = rsqrtf(vs * (1.f / 128.f) + 1e-5f);
        }
        #pragma unroll
        for (int nt = 0; nt < 8; ++nt) { gam[nt] = ln_g[nt * 16 + lo16]; bet[nt] = ln_b[nt * 16 + lo16]; }
    }
    __syncthreads();   // layer-1 A/B reads done
    if (wv < 2) {
        #pragma unroll
        for (int nt = 0; nt < 8; ++nt) {
            int cw = nt * 16 + lo16;
            int frag = wv * 4 + (cw >> 5);
            int lnf  = (((cw & 31) >> 3) * 16);
            #pragma unroll
            for (int i = 0; i < 4; ++i) {
                float h = fmaf((acc[nt][i] - mu_[i]) * rs_[i], gam[nt], bet[nt]);
                *((ushort*)((char*)sm.fb.Afr + frag * 1024 + ((g * 4 + i) + lnf) * 16 + (cw & 7) * 2)) = f2h(fmaxf(h, 0.f));
            }
        }
    }
    #pragma unroll
    for (int j = 0; j < 8; ++j) sm.fb.Bs[tid + j * 256] = breg[j];
    #pragma unroll
    for (int j = 0; j < 8; ++j) breg[j] = wsrc[4096 + tid + j * 256];
    __syncthreads();

    // ---- layer 2: agg = relu(h) @ Wa2 + ba2 ----
    if (wv < 2) {
        #pragma unroll
        for (int nt = 0; nt < 8; ++nt) {
            float bias = ba2[nt * 16 + lo16];
            acc[nt] = (f32x4){bias, bias, bias, bias};
        }
        mlp_gemm(acc, sm.fb.Afr, Bs, wv, l);
    }
    __syncthreads();   // layer-2 A/B reads done
    if (wv < 2) {
        #pragma unroll
        for (int nt = 0; nt < 8; ++nt) {
            int cw = nt * 16 + lo16;
            int frag = wv * 4 + (cw >> 5);
            int lnf  = (((cw & 31) >> 3) * 16);
            #pragma unroll
            for (int i = 0; i < 4; ++i)
                *((ushort*)((char*)sm.fb.Afr + frag * 1024 + ((g * 4 + i) + lnf) * 16 + (cw & 7) * 2)) = f2h(acc[nt][i]);
        }
    }
    #pragma unroll
    for (int j = 0; j < 8; ++j) sm.fb.Bs[tid + j * 256] = breg[j];
    __syncthreads();

    // ---- layer 3: infl = agg @ Wd + bd; gate = sigmoid -> gate2 (fp16) ----
    if (wv < 2) {
        #pragma unroll
        for (int nt = 0; nt < 8; ++nt) {
            float bias = bd[nt * 16 + lo16];
            acc[nt] = (f32x4){bias, bias, bias, bias};
        }
        mlp_gemm(acc, sm.fb.Afr, Bs, wv, l);
        #pragma unroll
        for (int i = 0; i < 4; ++i) {
            int row = c0 + wv * 16 + g * 4 + i;
            if (row < nC) {
                ushort* dst = gate2 + ((size_t)b * TT + row) * DD + lo16;
                #pragma unroll
                for (int nt = 0; nt < 8; ++nt)
                    dst[nt * 16] = f2h(1.f / (1.f + __expf(-acc[nt][i])));
            }
        }
    }
}

// ---------------------------------------------------------------------------
// Kernel 4: out[t] = fma(x[t], gate[seg[t]], x[t])  — gate now fp16.
// ---------------------------------------------------------------------------
__global__ __launch_bounds__(256) void k_out(const float* __restrict__ x,
    const int* __restrict__ seg, const ushort* __restrict__ gate2, float* __restrict__ out)
{
    const size_t idx = (size_t)blockIdx.x * 256 + threadIdx.x;
    const size_t tok = idx >> 5;
    const int d4 = (int)(idx & 31);
    const int b  = (int)(tok >> 14);
    const int sg = seg[tok];
    ushort4 gu = *(const ushort4*)(gate2 + (((size_t)b << 14) + sg) * DD + d4 * 4);
    float4 xv = ld4(x + tok * DD + (size_t)d4 * 4);
    float4 o;
    o.x = fmaf(xv.x, h2f(gu.x), xv.x);
    o.y = fmaf(xv.y, h2f(gu.y), xv.y);
    o.z = fmaf(xv.z, h2f(gu.z), xv.z);
    o.w = fmaf(xv.w, h2f(gu.w), xv.w);
    *(float4*)(out + idx * 4) = o;
}

extern "C" void kernel_launch(void* const* d_in, const int* in_sizes, int n_in,
                              void* d_out, int out_size, void* d_ws, size_t ws_size,
                              hipStream_t stream)
{
    (void)in_sizes; (void)n_in; (void)out_size; (void)ws_size;
    const float* x    = (const float*)d_in[0];
    const float* Wk   = (const float*)d_in[1];
    const float* bk   = (const float*)d_in[2];
    const float* Wq   = (const float*)d_in[3];
    const float* bq   = (const float*)d_in[4];
    const float* Wa1  = (const float*)d_in[5];
    const float* ba1  = (const float*)d_in[6];
    const float* ln_g = (const float*)d_in[7];
    const float* ln_b = (const float*)d_in[8];
    const float* Wa2  = (const float*)d_in[9];
    const float* ba2  = (const float*)d_in[10];
    const float* Wd   = (const float*)d_in[11];
    const float* bd   = (const float*)d_in[12];
    float* out = (float*)d_out;

    // ws layout
    char* p = (char*)d_ws;
    ushort* gate2 = (ushort*)p; p += (size_t)BB * TT * DD * 4;   // fp16 gate (32MB used of 64MB slot)
    int* seg     = (int*)p;     p += (size_t)BB * TT * 4;        // bind bits -> seg ids
    int* cs      = (int*)p;     p += (size_t)BB * (TT + 1) * 4;
    int* numC    = (int*)p;     p += 64;
    ushort* wfm  = (ushort*)p;  p += 3 * DD * DD * 2;            // MLP W frags fp16 (96 KB)
    ushort* wfb  = (ushort*)p;  p += DD * DD * 2;                // bind W frags fp16 (32 KB)
    int* flist   = (int*)p;     p += (size_t)FCAP * 4;           // fixup list (128 KB)
    int* fcnt    = (int*)p;

    k_wprep<<<dim3(32, 4), 64, 0, stream>>>(Wa1, Wa2, Wd, Wk, Wq, wfm, wfb, fcnt);
    k_bind<<<dim3(256, BB), 256, 0, stream>>>(x, wfb, bk, bq, seg, flist, fcnt);
    k_fixup<<<dim3(256), 256, 0, stream>>>(x, Wk, bk, Wq, bq, flist, fcnt, seg);
    k_scan<<<dim3(BB), 1024, 0, stream>>>(seg, seg, cs, numC);
    k_mlp<<<dim3(TT / 32, BB), 256, 0, stream>>>(x, cs, ba1, ln_g, ln_b, ba2, bd, wfm, numC, gate2);
    k_out<<<dim3(BB * TT * DD / (256 * 4)), 256, 0, stream>>>(x, seg, gate2, out);
}

// Round 13
// 138.292 us; speedup vs baseline: 1.1198x; 1.1198x over previous
//
#include <hip/hip_runtime.h>
#include <math.h>

#define BB 8
#define TT 16384
#define DD 128
#define DH 64
#define FCAP 32768
#define FMARGIN 0.05f

typedef _Float16 half8 __attribute__((ext_vector_type(8)));
typedef float f32x4 __attribute__((ext_vector_type(4)));

union H8 { half8 h; uint4 q; ushort us[8]; };

static __device__ __forceinline__ float4 ld4(const float* p) { return *(const float4*)p; }

// pack two floats as adjacent fp16 in a u32 (low = first)
static __device__ __forceinline__ uint pk2(float a, float b) {
    union { _Float16 f; ushort u; } A, B;
    A.f = (_Float16)a; B.f = (_Float16)b;
    return (uint)A.u | ((uint)B.u << 16);
}

// split 8 fp32 -> fp16 hi + fp16 lo (x = hi + lo exact to ~2^-22)
static __device__ __forceinline__ void split8h(const float4 v0, const float4 v1,
                                               half8* xh, half8* xl)
{
    float f[8] = {v0.x, v0.y, v0.z, v0.w, v1.x, v1.y, v1.z, v1.w};
    half8 h, l;
    #pragma unroll
    for (int j = 0; j < 8; ++j) {
        _Float16 hv = (_Float16)f[j];
        h[j] = hv;
        l[j] = (_Float16)(f[j] - (float)hv);
    }
    *xh = h; *xl = l;
}

// ---------------------------------------------------------------------------
// Kernel W-prep: weights fp32 -> fp16 MFMA B-fragment layout (single fp16).
// ---------------------------------------------------------------------------
__global__ __launch_bounds__(64) void k_wprep(
    const float* __restrict__ Wa1, const float* __restrict__ Wa2,
    const float* __restrict__ Wd, const float* __restrict__ Wk,
    const float* __restrict__ Wq, ushort* __restrict__ wfm,
    ushort* __restrict__ wfb, int* __restrict__ fcnt)
{
    const int l  = threadIdx.x;
    const int nt = blockIdx.x & 7;
    const int kb = blockIdx.x >> 3;
    const int ly = blockIdx.y;
    if (ly == 0 && blockIdx.x == 0 && l == 0) *fcnt = 0;
    const int n  = nt * 16 + (l & 15);
    const int k0 = kb * 32 + (l >> 4) * 8;
    H8 v;
    if (ly < 3) {
        const float* W = (ly == 0) ? Wa1 : (ly == 1) ? Wa2 : Wd;
        #pragma unroll
        for (int e = 0; e < 8; ++e) v.h[e] = (_Float16)W[(k0 + e) * DD + n];
        *(uint4*)(wfm + (size_t)(((ly * 8 + nt) * 4 + kb) * 64 + l) * 8) = v.q;
    } else {
        #pragma unroll
        for (int e = 0; e < 8; ++e) {
            float w = (n < 64) ? Wk[(k0 + e) * DH + n] : Wq[(k0 + e) * DH + n - 64];
            v.h[e] = (_Float16)w;
        }
        *(uint4*)(wfb + (size_t)((nt * 4 + kb) * 64 + l) * 8) = v.q;
    }
}

// ---------------------------------------------------------------------------
// Kernel 1: binding logits via fp16 MFMA, 2-product. (round-8 version)
// ---------------------------------------------------------------------------
__global__ __launch_bounds__(256, 2) void k_bind(
    const float* __restrict__ x, const ushort* __restrict__ wfb,
    const float* __restrict__ bk, const float* __restrict__ bq,
    int* __restrict__ cstart, int* __restrict__ flist, int* __restrict__ fcnt)
{
    __shared__ uint4 Bs4[2048];
    __shared__ float bnd[4][64];
    const int b    = blockIdx.y;
    const int tb   = blockIdx.x * 64;
    const int tid  = threadIdx.x;
    const int wv   = tid >> 6;
    const int l    = tid & 63;
    const int lo16 = l & 15;
    const int g    = l >> 4;

    {
        const uint4* wsrc = (const uint4*)wfb;
        #pragma unroll
        for (int j = 0; j < 8; ++j) { int idx = tid + j * 256; Bs4[idx] = wsrc[idx]; }
    }

    const float* xrow = x + ((size_t)b * TT + tb + wv * 16 + lo16) * DD;
    half8 xh[4], xl[4];
    #pragma unroll
    for (int kb = 0; kb < 4; ++kb) {
        float4 v0 = ld4(xrow + kb * 32 + g * 8);
        float4 v1 = ld4(xrow + kb * 32 + g * 8 + 4);
        split8h(v0, v1, &xh[kb], &xl[kb]);
    }
    int r64 = tb + 64; if (r64 > TT - 1) r64 = TT - 1;
    const float* xq = x + ((size_t)b * TT + r64) * DD;
    half8 qh[4], ql[4];
    H8 z; z.q.x = z.q.y = z.q.z = z.q.w = 0u;
    #pragma unroll
    for (int kb = 0; kb < 4; ++kb) {
        qh[kb] = z.h; ql[kb] = z.h;
        if (lo16 == 0) {
            float4 v0 = ld4(xq + kb * 32 + g * 8);
            float4 v1 = ld4(xq + kb * 32 + g * 8 + 4);
            split8h(v0, v1, &qh[kb], &ql[kb]);
        }
    }

    f32x4 acc[8];
    #pragma unroll
    for (int nt = 0; nt < 8; ++nt) {
        int col = nt * 16 + lo16;
        float bias = (col < 64) ? bk[col] : bq[col - 64];
        acc[nt] = (f32x4){bias, bias, bias, bias};
    }
    f32x4 acc4;
    {
        float bias = bq[wv * 16 + lo16];
        acc4 = (f32x4){bias, bias, bias, bias};
    }

    __syncthreads();
    const ushort* Bs = (const ushort*)Bs4;
    const ushort* Bs_halo = Bs + (size_t)((4 + wv) * 4 * 64 + l) * 8;
    #pragma unroll
    for (int kb = 0; kb < 4; ++kb) {
        half8 bh[8];
        #pragma unroll
        for (int nt = 0; nt < 8; ++nt)
            bh[nt] = *(const half8*)(Bs + (size_t)((nt * 4 + kb) * 64 + l) * 8);
        #pragma unroll
        for (int nt = 0; nt < 8; ++nt) {
            acc[nt] = __builtin_amdgcn_mfma_f32_16x16x32_f16(xh[kb], bh[nt], acc[nt], 0, 0, 0);
            acc[nt] = __builtin_amdgcn_mfma_f32_16x16x32_f16(xl[kb], bh[nt], acc[nt], 0, 0, 0);
        }
        half8 bh4 = *(const half8*)(Bs_halo + (size_t)kb * 64 * 8);
        acc4 = __builtin_amdgcn_mfma_f32_16x16x32_f16(qh[kb], bh4, acc4, 0, 0, 0);
        acc4 = __builtin_amdgcn_mfma_f32_16x16x32_f16(ql[kb], bh4, acc4, 0, 0, 0);
    }

    if (l < 16) {
        if (wv > 0) {
            #pragma unroll
            for (int nt = 0; nt < 4; ++nt) bnd[wv - 1][nt * 16 + lo16] = acc[4 + nt][0];
        }
        bnd[3][wv * 16 + lo16] = acc4[0];
    }
    __syncthreads();

    float qn3[4];
    #pragma unroll
    for (int nt = 0; nt < 4; ++nt) qn3[nt] = __shfl_down(acc[4 + nt][0], 16);
    if (g == 3) {
        #pragma unroll
        for (int nt = 0; nt < 4; ++nt) qn3[nt] = bnd[wv][nt * 16 + lo16];
    }
    float s[4];
    #pragma unroll
    for (int i = 0; i < 3; ++i) {
        float t = 0.f;
        #pragma unroll
        for (int nt = 0; nt < 4; ++nt) t += acc[nt][i] * acc[4 + nt][i + 1];
        s[i] = t;
    }
    {
        float t = 0.f;
        #pragma unroll
        for (int nt = 0; nt < 4; ++nt) t += acc[nt][3] * qn3[nt];
        s[3] = t;
    }
    #pragma unroll
    for (int i = 0; i < 4; ++i) {
        #pragma unroll
        for (int m = 1; m < 16; m <<= 1) s[i] += __shfl_xor(s[i], m);
    }
    if (lo16 == 0) {
        #pragma unroll
        for (int i = 0; i < 4; ++i) {
            int t = tb + wv * 16 + g * 4 + i;
            if (t <= TT - 2) {
                cstart[b * TT + t + 1] = (s[i] > 0.f) ? 0 : 1;
                if (fabsf(s[i]) < FMARGIN) {
                    int pos = atomicAdd(fcnt, 1);
                    if (pos < FCAP) flist[pos] = b * TT + t;
                }
            }
        }
    }
    if (blockIdx.x == 0 && tid == 0) cstart[b * TT] = 1;
}

// ---------------------------------------------------------------------------
// Kernel 1b: exact fp32 recompute of flagged borderline bind decisions.
// ---------------------------------------------------------------------------
__global__ __launch_bounds__(256) void k_fixup(
    const float* __restrict__ x, const float* __restrict__ Wk, const float* __restrict__ bk,
    const float* __restrict__ Wq, const float* __restrict__ bq,
    const int* __restrict__ flist, const int* __restrict__ fcnt, int* __restrict__ cstart)
{
    const int n    = min(*fcnt, FCAP);
    const int wv   = (blockIdx.x * 256 + threadIdx.x) >> 6;
    const int lane = threadIdx.x & 63;
    const int nwv  = gridDim.x * 4;
    for (int i = wv; i < n; i += nwv) {
        int idx = flist[i];
        int b = idx >> 14;
        int t = idx & (TT - 1);
        const float* xt = x + ((size_t)b * TT + t) * DD;
        float K = bk[lane], Q = bq[lane];
        #pragma unroll 8
        for (int k = 0; k < DD; ++k) {
            K = fmaf(xt[k],      Wk[k * DH + lane], K);
            Q = fmaf(xt[DD + k], Wq[k * DH + lane], Q);
        }
        float p = K * Q;
        #pragma unroll
        for (int m = 1; m < 64; m <<= 1) p += __shfl_xor(p, m);
        if (lane == 0) cstart[b * TT + t + 1] = (p > 0.f) ? 0 : 1;
    }
}

// ---------------------------------------------------------------------------
// Kernel 2: per-batch scan -> seg, chunk-start table, counts. (unchanged)
// ---------------------------------------------------------------------------
__global__ __launch_bounds__(1024) void k_scan(const int* __restrict__ cstart,
    int* __restrict__ seg, int* __restrict__ cs, int* __restrict__ numC)
{
    __shared__ int wsum[16];
    const int b = blockIdx.x, tid = threadIdx.x;
    const int wv = tid >> 6, lane = tid & 63;
    const int base = b * TT + tid * 16;
    int v[16];
    #pragma unroll
    for (int i = 0; i < 4; ++i) {
        int4 q = *(const int4*)(cstart + base + i * 4);
        v[i * 4 + 0] = q.x; v[i * 4 + 1] = q.y; v[i * 4 + 2] = q.z; v[i * 4 + 3] = q.w;
    }
    int s[16]; int run = 0;
    #pragma unroll
    for (int i = 0; i < 16; ++i) { run += v[i]; s[i] = run; }
    int incl = run;
    #pragma unroll
    for (int off = 1; off < 64; off <<= 1) {
        int t = __shfl_up(incl, off);
        if (lane >= off) incl += t;
    }
    if (lane == 63) wsum[wv] = incl;
    __syncthreads();
    if (tid < 16) {
        int w = wsum[tid];
        #pragma unroll
        for (int off = 1; off < 16; off <<= 1) {
            int t = __shfl_up(w, off, 16);
            if (tid >= off) w += t;
        }
        wsum[tid] = w;
    }
    __syncthreads();
    const int excl = (wv ? wsum[wv - 1] : 0) + incl - run;
    #pragma unroll
    for (int i = 0; i < 16; ++i) {
        int sg = excl + s[i] - 1;
        seg[base + i] = sg;
        if (v[i]) cs[b * (TT + 1) + sg] = tid * 16 + i;
    }
    if (tid == 1023) {
        int tot = excl + run;
        numC[b] = tot;
        cs[b * (TT + 1) + tot] = TT;
    }
}

// ---------------------------------------------------------------------------
// k_mlp GEMM: acc[8] = A(fp16 frags in LDS) @ B(fp16 frags in LDS).
// ---------------------------------------------------------------------------
__device__ __forceinline__ void mlp_gemm(f32x4 acc[8], const uint4* Afr4,
    const ushort* Bs, int wv, int l)
{
    half8 af[4];
    #pragma unroll
    for (int kb = 0; kb < 4; ++kb)
        af[kb] = *(const half8*)((const char*)Afr4 + ((wv * 4 + kb) * 64 + l) * 16);
    #pragma unroll
    for (int kb = 0; kb < 4; ++kb) {
        half8 bh[8];
        #pragma unroll
        for (int nt = 0; nt < 8; ++nt)
            bh[nt] = *(const half8*)(Bs + (size_t)((nt * 4 + kb) * 64 + l) * 8);
        #pragma unroll
        for (int nt = 0; nt < 8; ++nt)
            acc[nt] = __builtin_amdgcn_mfma_f32_16x16x32_f16(af[kb], bh[nt], acc[nt], 0, 0, 0);
    }
}

// ---------------------------------------------------------------------------
// Kernel 3: per-chunk MLP via fp16 MFMA (round-10 structure: 64 chunks/block,
// all-wave GEMM, fp32 gate). CHANGE vs r10: phase 1 is a DOUBLE-BUFFERED
// 32-token pipeline — per tile: issue next tile's loads into registers
// (issue-early), reduce current tile from LDS, ds_write next tile
// (write-late), ONE barrier. Hides the global-load drain under the reduce.
// ---------------------------------------------------------------------------
__global__ __launch_bounds__(256, 2) void k_mlp(
    const float* __restrict__ x, const int* __restrict__ cs,
    const float* __restrict__ ba1, const float* __restrict__ ln_g, const float* __restrict__ ln_b,
    const float* __restrict__ ba2, const float* __restrict__ bd,
    const ushort* __restrict__ wfm, const int* __restrict__ numC, float* __restrict__ cm)
{
    __shared__ union {
        float Tok[2][32 * 132];                            // 2 x 16896 B token tiles
        struct { uint4 Afr[1024]; uint4 Bs[2048]; } fb;    // 49152 B frags
    } sm;
    const int b  = blockIdx.y;
    const int nC = numC[b];
    const int c0 = blockIdx.x * 64;
    if (c0 >= nC) return;
    const int tid  = threadIdx.x;
    const int wv   = tid >> 6;
    const int l    = tid & 63;
    const int lo16 = l & 15;
    const int g    = l >> 4;
    const ushort* Bs = (const ushort*)sm.fb.Bs;
    const uint4* wsrc = (const uint4*)wfm;

    // pre-issue B layer 0 into registers (hides under phase 1)
    uint4 breg[8];
    #pragma unroll
    for (int j = 0; j < 8; ++j) breg[j] = wsrc[tid + j * 256];

    // ---- phase 1: chunk means, double-buffered 32-token tiles ----
    const int cbase = b * (TT + 1);
    const int T0 = cs[cbase + c0];
    const int cEnd = (c0 + 64 < nC) ? (c0 + 64) : nC;
    const int T1 = cs[cbase + cEnd];
    int t0r[8], t1r[8];
    #pragma unroll
    for (int ii = 0; ii < 8; ++ii) {
        int r = (tid + ii * 256) >> 5;
        int c = c0 + r;
        t0r[ii] = (c < nC) ? cs[cbase + c] : 0;
        t1r[ii] = (c < nC) ? cs[cbase + c + 1] : 0;
    }
    float4 vals[8];
    #pragma unroll
    for (int ii = 0; ii < 8; ++ii) vals[ii] = make_float4(0.f, 0.f, 0.f, 0.f);

    // prologue: stage tile 0 into Tok[0]
    {
        int tEnd0 = (T0 + 32 < T1) ? (T0 + 32) : T1;
        for (int j = tid; j < (tEnd0 - T0) * 32; j += 256) {
            int trow = j >> 5, c4 = (j & 31) * 4;
            *(float4*)&sm.Tok[0][trow * 132 + c4] =
                ld4(x + ((size_t)b * TT + T0 + trow) * DD + c4);
        }
    }
    int buf = 0;
    for (int tt = T0; tt < T1; tt += 32) {
        __syncthreads();                       // Tok[buf] staged; Tok[buf^1] reads done
        const int tEnd = (tt + 32 < T1) ? (tt + 32) : T1;
        // issue next tile's loads into registers (static 4 slots, rule-#20 safe)
        float4 ldv[4]; int ldst[4];
        const int nEnd = (tt + 64 < T1) ? (tt + 64) : T1;
        const int nwords = (tt + 32 < T1) ? (nEnd - (tt + 32)) * 32 : 0;
        #pragma unroll
        for (int k2 = 0; k2 < 4; ++k2) {
            int j = tid + k2 * 256;
            ldst[k2] = -1;
            ldv[k2] = make_float4(0.f, 0.f, 0.f, 0.f);
            if (j < nwords) {
                int trow = j >> 5, c4 = (j & 31) * 4;
                ldv[k2] = ld4(x + ((size_t)b * TT + tt + 32 + trow) * DD + c4);
                ldst[k2] = trow * 132 + c4;
            }
        }
        // reduce current tile from Tok[buf]
        #pragma unroll
        for (int ii = 0; ii < 8; ++ii) {
            int c4 = ((tid + ii * 256) & 31) * 4;
            int lo = (t0r[ii] > tt)   ? t0r[ii] : tt;
            int hi = (t1r[ii] < tEnd) ? t1r[ii] : tEnd;
            for (int t = lo; t < hi; ++t) {
                const float* ap = &sm.Tok[buf][(t - tt) * 132 + c4];
                vals[ii].x += ap[0]; vals[ii].y += ap[1];
                vals[ii].z += ap[2]; vals[ii].w += ap[3];
            }
        }
        // write next tile (write-late)
        #pragma unroll
        for (int k2 = 0; k2 < 4; ++k2)
            if (ldst[k2] >= 0) *(float4*)&sm.Tok[buf ^ 1][ldst[k2]] = ldv[k2];
        buf ^= 1;
    }
    __syncthreads();                           // all Tok reads done; union flips to frags

    // write B0 from regs; divide means; pack fp16 A-frags; pre-issue B1
    #pragma unroll
    for (int j = 0; j < 8; ++j) sm.fb.Bs[tid + j * 256] = breg[j];
    #pragma unroll
    for (int ii = 0; ii < 8; ++ii) {
        int i = tid + ii * 256;
        int r = i >> 5, c4 = (i & 31) * 4;
        float4 sv = make_float4(0.f, 0.f, 0.f, 0.f);
        if (c0 + r < nC) {
            float inv = 1.f / (float)(t1r[ii] - t0r[ii]);
            sv.x = vals[ii].x * inv; sv.y = vals[ii].y * inv;
            sv.z = vals[ii].z * inv; sv.w = vals[ii].w * inv;
        }
        int frag = (r >> 4) * 4 + (c4 >> 5);
        int lanef = (r & 15) + (((c4 & 31) >> 3) * 16);
        uint2 pk = make_uint2(pk2(sv.x, sv.y), pk2(sv.z, sv.w));
        *(uint2*)((char*)sm.fb.Afr + frag * 1024 + lanef * 16 + (c4 & 7) * 2) = pk;
    }
    #pragma unroll
    for (int j = 0; j < 8; ++j) breg[j] = wsrc[2048 + tid + j * 256];
    __syncthreads();

    // ---- layer 1: h = cm @ Wa1 + ba1; LayerNorm; ReLU ----
    f32x4 acc[8];
    #pragma unroll
    for (int nt = 0; nt < 8; ++nt) {
        float bias = ba1[nt * 16 + lo16];
        acc[nt] = (f32x4){bias, bias, bias, bias};
    }
    mlp_gemm(acc, sm.fb.Afr, Bs, wv, l);

    float mu_[4], rs_[4];
    #pragma unroll
    for (int i = 0; i < 4; ++i) {
        float smv = 0.f;
        #pragma unroll
        for (int nt = 0; nt < 8; ++nt) smv += acc[nt][i];
        #pragma unroll
        for (int k = 1; k < 16; k <<= 1) smv += __shfl_xor(smv, k, 16);
        mu_[i] = smv * (1.f / 128.f);
        float vs = 0.f;
        #pragma unroll
        for (int nt = 0; nt < 8; ++nt) { float d = acc[nt][i] - mu_[i]; vs += d * d; }
        #pragma unroll
        for (int k = 1; k < 16; k <<= 1) vs += __shfl_xor(vs, k, 16);
        rs_[i] = rsqrtf(vs * (1.f / 128.f) + 1e-5f);
    }
    float gam[8], bet[8];
    #pragma unroll
    for (int nt = 0; nt < 8; ++nt) { gam[nt] = ln_g[nt * 16 + lo16]; bet[nt] = ln_b[nt * 16 + lo16]; }

    __syncthreads();   // layer-1 A/B reads done
    #pragma unroll
    for (int nt = 0; nt < 8; ++nt) {
        int cw = nt * 16 + lo16;
        int frag = wv * 4 + (cw >> 5);
        int lnf  = (((cw & 31) >> 3) * 16);
        #pragma unroll
        for (int i = 0; i < 4; ++i) {
            float h = fmaf((acc[nt][i] - mu_[i]) * rs_[i], gam[nt], bet[nt]);
            union { _Float16 f; ushort u; } cv; cv.f = (_Float16)fmaxf(h, 0.f);
            *((ushort*)((char*)sm.fb.Afr + frag * 1024 + ((g * 4 + i) + lnf) * 16 + (cw & 7) * 2)) = cv.u;
        }
    }
    #pragma unroll
    for (int j = 0; j < 8; ++j) sm.fb.Bs[tid + j * 256] = breg[j];
    #pragma unroll
    for (int j = 0; j < 8; ++j) breg[j] = wsrc[4096 + tid + j * 256];
    __syncthreads();

    // ---- layer 2: agg = relu(h) @ Wa2 + ba2 ----
    #pragma unroll
    for (int nt = 0; nt < 8; ++nt) {
        float bias = ba2[nt * 16 + lo16];
        acc[nt] = (f32x4){bias, bias, bias, bias};
    }
    mlp_gemm(acc, sm.fb.Afr, Bs, wv, l);
    __syncthreads();   // layer-2 A/B reads done
    #pragma unroll
    for (int nt = 0; nt < 8; ++nt) {
        int cw = nt * 16 + lo16;
        int frag = wv * 4 + (cw >> 5);
        int lnf  = (((cw & 31) >> 3) * 16);
        #pragma unroll
        for (int i = 0; i < 4; ++i) {
            union { _Float16 f; ushort u; } cv; cv.f = (_Float16)acc[nt][i];
            *((ushort*)((char*)sm.fb.Afr + frag * 1024 + ((g * 4 + i) + lnf) * 16 + (cw & 7) * 2)) = cv.u;
        }
    }
    #pragma unroll
    for (int j = 0; j < 8; ++j) sm.fb.Bs[tid + j * 256] = breg[j];
    __syncthreads();

    // ---- layer 3: infl = agg @ Wd + bd; gate = sigmoid -> cm (fp32) ----
    #pragma unroll
    for (int nt = 0; nt < 8; ++nt) {
        float bias = bd[nt * 16 + lo16];
        acc[nt] = (f32x4){bias, bias, bias, bias};
    }
    mlp_gemm(acc, sm.fb.Afr, Bs, wv, l);
    #pragma unroll
    for (int i = 0; i < 4; ++i) {
        int row = c0 + wv * 16 + g * 4 + i;
        if (row < nC) {
            float* dst = cm + ((size_t)b * TT + row) * DD + lo16;
            #pragma unroll
            for (int nt = 0; nt < 8; ++nt)
                dst[nt * 16] = 1.f / (1.f + __expf(-acc[nt][i]));
        }
    }
}

// ---------------------------------------------------------------------------
// Kernel 4: out[t] = fma(x[t], gate[seg[t]], x[t])  (round-10 version)
// ---------------------------------------------------------------------------
__global__ __launch_bounds__(256) void k_out(const float* __restrict__ x,
    const int* __restrict__ seg, const float* __restrict__ gate, float* __restrict__ out)
{
    const size_t idx = (size_t)blockIdx.x * 256 + threadIdx.x;
    const size_t tok = idx >> 5;
    const int d4 = (int)(idx & 31);
    const int b  = (int)(tok >> 14);
    const int sg = seg[tok];
    float4 gv = ld4(gate + (((size_t)b << 14) + sg) * DD + d4 * 4);
    float4 xv = ld4(x + tok * DD + (size_t)d4 * 4);
    float4 o;
    o.x = fmaf(xv.x, gv.x, xv.x);
    o.y = fmaf(xv.y, gv.y, xv.y);
    o.z = fmaf(xv.z, gv.z, xv.z);
    o.w = fmaf(xv.w, gv.w, xv.w);
    *(float4*)(out + idx * 4) = o;
}

extern "C" void kernel_launch(void* const* d_in, const int* in_sizes, int n_in,
                              void* d_out, int out_size, void* d_ws, size_t ws_size,
                              hipStream_t stream)
{
    (void)in_sizes; (void)n_in; (void)out_size; (void)ws_size;
    const float* x    = (const float*)d_in[0];
    const float* Wk   = (const float*)d_in[1];
    const float* bk   = (const float*)d_in[2];
    const float* Wq   = (const float*)d_in[3];
    const float* bq   = (const float*)d_in[4];
    const float* Wa1  = (const float*)d_in[5];
    const float* ba1  = (const float*)d_in[6];
    const float* ln_g = (const float*)d_in[7];
    const float* ln_b = (const float*)d_in[8];
    const float* Wa2  = (const float*)d_in[9];
    const float* ba2  = (const float*)d_in[10];
    const float* Wd   = (const float*)d_in[11];
    const float* bd   = (const float*)d_in[12];
    float* out = (float*)d_out;

    // ws layout
    char* p = (char*)d_ws;
    float* cm    = (float*)p;   p += (size_t)BB * TT * DD * 4;   // 64 MB (gate)
    int* seg     = (int*)p;     p += (size_t)BB * TT * 4;        // bind bits -> seg ids
    int* cs      = (int*)p;     p += (size_t)BB * (TT + 1) * 4;
    int* numC    = (int*)p;     p += 64;
    ushort* wfm  = (ushort*)p;  p += 3 * DD * DD * 2;            // MLP W frags fp16 (96 KB)
    ushort* wfb  = (ushort*)p;  p += DD * DD * 2;                // bind W frags fp16 (32 KB)
    int* flist   = (int*)p;     p += (size_t)FCAP * 4;           // fixup list (128 KB)
    int* fcnt    = (int*)p;

    k_wprep<<<dim3(32, 4), 64, 0, stream>>>(Wa1, Wa2, Wd, Wk, Wq, wfm, wfb, fcnt);
    k_bind<<<dim3(256, BB), 256, 0, stream>>>(x, wfb, bk, bq, seg, flist, fcnt);
    k_fixup<<<dim3(256), 256, 0, stream>>>(x, Wk, bk, Wq, bq, flist, fcnt, seg);
    k_scan<<<dim3(BB), 1024, 0, stream>>>(seg, seg, cs, numC);
    k_mlp<<<dim3(TT / 64, BB), 256, 0, stream>>>(x, cs, ba1, ln_g, ln_b, ba2, bd, wfm, numC, cm);
    k_out<<<dim3(BB * TT * DD / (256 * 4)), 256, 0, stream>>>(x, seg, cm, out);
}

// Round 14
// 124.910 us; speedup vs baseline: 1.2397x; 1.1071x over previous
//
#include <hip/hip_runtime.h>
#include <math.h>

#define BB 8
#define TT 16384
#define DD 128
#define DH 64
#define FCAP 32768
#define FMARGIN 0.05f

typedef _Float16 half8 __attribute__((ext_vector_type(8)));
typedef float f32x4 __attribute__((ext_vector_type(4)));

union H8 { half8 h; uint4 q; ushort us[8]; };

static __device__ __forceinline__ float4 ld4(const float* p) { return *(const float4*)p; }

// pack two floats as adjacent fp16 in a u32 (low = first)
static __device__ __forceinline__ uint pk2(float a, float b) {
    union { _Float16 f; ushort u; } A, B;
    A.f = (_Float16)a; B.f = (_Float16)b;
    return (uint)A.u | ((uint)B.u << 16);
}

// split 8 fp32 -> fp16 hi + fp16 lo (x = hi + lo exact to ~2^-22)
static __device__ __forceinline__ void split8h(const float4 v0, const float4 v1,
                                               half8* xh, half8* xl)
{
    float f[8] = {v0.x, v0.y, v0.z, v0.w, v1.x, v1.y, v1.z, v1.w};
    half8 h, l;
    #pragma unroll
    for (int j = 0; j < 8; ++j) {
        _Float16 hv = (_Float16)f[j];
        h[j] = hv;
        l[j] = (_Float16)(f[j] - (float)hv);
    }
    *xh = h; *xl = l;
}

// ---------------------------------------------------------------------------
// Kernel W-prep: weights fp32 -> fp16 MFMA B-fragment layout (single fp16).
// ---------------------------------------------------------------------------
__global__ __launch_bounds__(64) void k_wprep(
    const float* __restrict__ Wa1, const float* __restrict__ Wa2,
    const float* __restrict__ Wd, const float* __restrict__ Wk,
    const float* __restrict__ Wq, ushort* __restrict__ wfm,
    ushort* __restrict__ wfb, int* __restrict__ fcnt)
{
    const int l  = threadIdx.x;
    const int nt = blockIdx.x & 7;
    const int kb = blockIdx.x >> 3;
    const int ly = blockIdx.y;
    if (ly == 0 && blockIdx.x == 0 && l == 0) *fcnt = 0;
    const int n  = nt * 16 + (l & 15);
    const int k0 = kb * 32 + (l >> 4) * 8;
    H8 v;
    if (ly < 3) {
        const float* W = (ly == 0) ? Wa1 : (ly == 1) ? Wa2 : Wd;
        #pragma unroll
        for (int e = 0; e < 8; ++e) v.h[e] = (_Float16)W[(k0 + e) * DD + n];
        *(uint4*)(wfm + (size_t)(((ly * 8 + nt) * 4 + kb) * 64 + l) * 8) = v.q;
    } else {
        #pragma unroll
        for (int e = 0; e < 8; ++e) {
            float w = (n < 64) ? Wk[(k0 + e) * DH + n] : Wq[(k0 + e) * DH + n - 64];
            v.h[e] = (_Float16)w;
        }
        *(uint4*)(wfb + (size_t)((nt * 4 + kb) * 64 + l) * 8) = v.q;
    }
}

// ---------------------------------------------------------------------------
// Kernel 1: binding logits via fp16 MFMA, 2-product. (round-8/10 version)
// ---------------------------------------------------------------------------
__global__ __launch_bounds__(256, 2) void k_bind(
    const float* __restrict__ x, const ushort* __restrict__ wfb,
    const float* __restrict__ bk, const float* __restrict__ bq,
    int* __restrict__ cstart, int* __restrict__ flist, int* __restrict__ fcnt)
{
    __shared__ uint4 Bs4[2048];
    __shared__ float bnd[4][64];
    const int b    = blockIdx.y;
    const int tb   = blockIdx.x * 64;
    const int tid  = threadIdx.x;
    const int wv   = tid >> 6;
    const int l    = tid & 63;
    const int lo16 = l & 15;
    const int g    = l >> 4;

    {
        const uint4* wsrc = (const uint4*)wfb;
        #pragma unroll
        for (int j = 0; j < 8; ++j) { int idx = tid + j * 256; Bs4[idx] = wsrc[idx]; }
    }

    const float* xrow = x + ((size_t)b * TT + tb + wv * 16 + lo16) * DD;
    half8 xh[4], xl[4];
    #pragma unroll
    for (int kb = 0; kb < 4; ++kb) {
        float4 v0 = ld4(xrow + kb * 32 + g * 8);
        float4 v1 = ld4(xrow + kb * 32 + g * 8 + 4);
        split8h(v0, v1, &xh[kb], &xl[kb]);
    }
    int r64 = tb + 64; if (r64 > TT - 1) r64 = TT - 1;
    const float* xq = x + ((size_t)b * TT + r64) * DD;
    half8 qh[4], ql[4];
    H8 z; z.q.x = z.q.y = z.q.z = z.q.w = 0u;
    #pragma unroll
    for (int kb = 0; kb < 4; ++kb) {
        qh[kb] = z.h; ql[kb] = z.h;
        if (lo16 == 0) {
            float4 v0 = ld4(xq + kb * 32 + g * 8);
            float4 v1 = ld4(xq + kb * 32 + g * 8 + 4);
            split8h(v0, v1, &qh[kb], &ql[kb]);
        }
    }

    f32x4 acc[8];
    #pragma unroll
    for (int nt = 0; nt < 8; ++nt) {
        int col = nt * 16 + lo16;
        float bias = (col < 64) ? bk[col] : bq[col - 64];
        acc[nt] = (f32x4){bias, bias, bias, bias};
    }
    f32x4 acc4;
    {
        float bias = bq[wv * 16 + lo16];
        acc4 = (f32x4){bias, bias, bias, bias};
    }

    __syncthreads();
    const ushort* Bs = (const ushort*)Bs4;
    const ushort* Bs_halo = Bs + (size_t)((4 + wv) * 4 * 64 + l) * 8;
    #pragma unroll
    for (int kb = 0; kb < 4; ++kb) {
        half8 bh[8];
        #pragma unroll
        for (int nt = 0; nt < 8; ++nt)
            bh[nt] = *(const half8*)(Bs + (size_t)((nt * 4 + kb) * 64 + l) * 8);
        #pragma unroll
        for (int nt = 0; nt < 8; ++nt) {
            acc[nt] = __builtin_amdgcn_mfma_f32_16x16x32_f16(xh[kb], bh[nt], acc[nt], 0, 0, 0);
            acc[nt] = __builtin_amdgcn_mfma_f32_16x16x32_f16(xl[kb], bh[nt], acc[nt], 0, 0, 0);
        }
        half8 bh4 = *(const half8*)(Bs_halo + (size_t)kb * 64 * 8);
        acc4 = __builtin_amdgcn_mfma_f32_16x16x32_f16(qh[kb], bh4, acc4, 0, 0, 0);
        acc4 = __builtin_amdgcn_mfma_f32_16x16x32_f16(ql[kb], bh4, acc4, 0, 0, 0);
    }

    if (l < 16) {
        if (wv > 0) {
            #pragma unroll
            for (int nt = 0; nt < 4; ++nt) bnd[wv - 1][nt * 16 + lo16] = acc[4 + nt][0];
        }
        bnd[3][wv * 16 + lo16] = acc4[0];
    }
    __syncthreads();

    float qn3[4];
    #pragma unroll
    for (int nt = 0; nt < 4; ++nt) qn3[nt] = __shfl_down(acc[4 + nt][0], 16);
    if (g == 3) {
        #pragma unroll
        for (int nt = 0; nt < 4; ++nt) qn3[nt] = bnd[wv][nt * 16 + lo16];
    }
    float s[4];
    #pragma unroll
    for (int i = 0; i < 3; ++i) {
        float t = 0.f;
        #pragma unroll
        for (int nt = 0; nt < 4; ++nt) t += acc[nt][i] * acc[4 + nt][i + 1];
        s[i] = t;
    }
    {
        float t = 0.f;
        #pragma unroll
        for (int nt = 0; nt < 4; ++nt) t += acc[nt][3] * qn3[nt];
        s[3] = t;
    }
    #pragma unroll
    for (int i = 0; i < 4; ++i) {
        #pragma unroll
        for (int m = 1; m < 16; m <<= 1) s[i] += __shfl_xor(s[i], m);
    }
    if (lo16 == 0) {
        #pragma unroll
        for (int i = 0; i < 4; ++i) {
            int t = tb + wv * 16 + g * 4 + i;
            if (t <= TT - 2) {
                cstart[b * TT + t + 1] = (s[i] > 0.f) ? 0 : 1;
                if (fabsf(s[i]) < FMARGIN) {
                    int pos = atomicAdd(fcnt, 1);
                    if (pos < FCAP) flist[pos] = b * TT + t;
                }
            }
        }
    }
    if (blockIdx.x == 0 && tid == 0) cstart[b * TT] = 1;
}

// ---------------------------------------------------------------------------
// Kernel 1b: exact fp32 recompute of flagged borderline bind decisions.
// ---------------------------------------------------------------------------
__global__ __launch_bounds__(256) void k_fixup(
    const float* __restrict__ x, const float* __restrict__ Wk, const float* __restrict__ bk,
    const float* __restrict__ Wq, const float* __restrict__ bq,
    const int* __restrict__ flist, const int* __restrict__ fcnt, int* __restrict__ cstart)
{
    const int n    = min(*fcnt, FCAP);
    const int wv   = (blockIdx.x * 256 + threadIdx.x) >> 6;
    const int lane = threadIdx.x & 63;
    const int nwv  = gridDim.x * 4;
    for (int i = wv; i < n; i += nwv) {
        int idx = flist[i];
        int b = idx >> 14;
        int t = idx & (TT - 1);
        const float* xt = x + ((size_t)b * TT + t) * DD;
        float K = bk[lane], Q = bq[lane];
        #pragma unroll 8
        for (int k = 0; k < DD; ++k) {
            K = fmaf(xt[k],      Wk[k * DH + lane], K);
            Q = fmaf(xt[DD + k], Wq[k * DH + lane], Q);
        }
        float p = K * Q;
        #pragma unroll
        for (int m = 1; m < 64; m <<= 1) p += __shfl_xor(p, m);
        if (lane == 0) cstart[b * TT + t + 1] = (p > 0.f) ? 0 : 1;
    }
}

// ---------------------------------------------------------------------------
// Kernel 2: per-batch scan -> seg, chunk-start table, counts. (unchanged)
// ---------------------------------------------------------------------------
__global__ __launch_bounds__(1024) void k_scan(const int* __restrict__ cstart,
    int* __restrict__ seg, int* __restrict__ cs, int* __restrict__ numC)
{
    __shared__ int wsum[16];
    const int b = blockIdx.x, tid = threadIdx.x;
    const int wv = tid >> 6, lane = tid & 63;
    const int base = b * TT + tid * 16;
    int v[16];
    #pragma unroll
    for (int i = 0; i < 4; ++i) {
        int4 q = *(const int4*)(cstart + base + i * 4);
        v[i * 4 + 0] = q.x; v[i * 4 + 1] = q.y; v[i * 4 + 2] = q.z; v[i * 4 + 3] = q.w;
    }
    int s[16]; int run = 0;
    #pragma unroll
    for (int i = 0; i < 16; ++i) { run += v[i]; s[i] = run; }
    int incl = run;
    #pragma unroll
    for (int off = 1; off < 64; off <<= 1) {
        int t = __shfl_up(incl, off);
        if (lane >= off) incl += t;
    }
    if (lane == 63) wsum[wv] = incl;
    __syncthreads();
    if (tid < 16) {
        int w = wsum[tid];
        #pragma unroll
        for (int off = 1; off < 16; off <<= 1) {
            int t = __shfl_up(w, off, 16);
            if (tid >= off) w += t;
        }
        wsum[tid] = w;
    }
    __syncthreads();
    const int excl = (wv ? wsum[wv - 1] : 0) + incl - run;
    #pragma unroll
    for (int i = 0; i < 16; ++i) {
        int sg = excl + s[i] - 1;
        seg[base + i] = sg;
        if (v[i]) cs[b * (TT + 1) + sg] = tid * 16 + i;
    }
    if (tid == 1023) {
        int tot = excl + run;
        numC[b] = tot;
        cs[b * (TT + 1) + tot] = TT;
    }
}

// ---------------------------------------------------------------------------
// Kernel 3a (NEW SPLIT): chunk means via 32-token LDS tiles. LDS = 16.9 KB
// -> 8 blocks/CU resident (vs 3 inside the old fused k_mlp): the per-tile
// barrier chain interleaves 8-deep. Means written fp32/float4 to cm
// (sector-aligned; r12 lesson). Same fp32 sum order as always.
// ---------------------------------------------------------------------------
__global__ __launch_bounds__(256) void k_meanp(const float* __restrict__ x,
    const int* __restrict__ cs, const int* __restrict__ numC, float* __restrict__ cm)
{
    __shared__ float Tok[32 * 132];            // 16896 B
    const int b  = blockIdx.y;
    const int nC = numC[b];
    const int c0 = blockIdx.x * 64;
    if (c0 >= nC) return;
    const int tid = threadIdx.x;
    const int cbase = b * (TT + 1);
    const int T0 = cs[cbase + c0];
    const int cEnd = (c0 + 64 < nC) ? (c0 + 64) : nC;
    const int T1 = cs[cbase + cEnd];
    int t0r[8], t1r[8];
    #pragma unroll
    for (int ii = 0; ii < 8; ++ii) {
        int r = (tid + ii * 256) >> 5;
        int c = c0 + r;
        t0r[ii] = (c < nC) ? cs[cbase + c] : 0;
        t1r[ii] = (c < nC) ? cs[cbase + c + 1] : 0;
    }
    float4 vals[8];
    #pragma unroll
    for (int ii = 0; ii < 8; ++ii) vals[ii] = make_float4(0.f, 0.f, 0.f, 0.f);

    for (int tt = T0; tt < T1; tt += 32) {
        __syncthreads();                       // prior tile reads done
        const int tEnd = (tt + 32 < T1) ? (tt + 32) : T1;
        for (int j = tid; j < (tEnd - tt) * 32; j += 256) {
            int trow = j >> 5, c4 = (j & 31) * 4;
            *(float4*)&Tok[trow * 132 + c4] =
                ld4(x + ((size_t)b * TT + tt + trow) * DD + c4);
        }
        __syncthreads();
        #pragma unroll
        for (int ii = 0; ii < 8; ++ii) {
            int c4 = ((tid + ii * 256) & 31) * 4;
            int lo = (t0r[ii] > tt)   ? t0r[ii] : tt;
            int hi = (t1r[ii] < tEnd) ? t1r[ii] : tEnd;
            for (int t = lo; t < hi; ++t) {
                const float* ap = &Tok[(t - tt) * 132 + c4];
                vals[ii].x += ap[0]; vals[ii].y += ap[1];
                vals[ii].z += ap[2]; vals[ii].w += ap[3];
            }
        }
    }
    // write means (float4, coalesced)
    #pragma unroll
    for (int ii = 0; ii < 8; ++ii) {
        int i = tid + ii * 256;
        int r = i >> 5, c4 = (i & 31) * 4;
        int c = c0 + r;
        if (c < nC) {
            float inv = 1.f / (float)(t1r[ii] - t0r[ii]);
            float4 sv;
            sv.x = vals[ii].x * inv; sv.y = vals[ii].y * inv;
            sv.z = vals[ii].z * inv; sv.w = vals[ii].w * inv;
            *(float4*)(cm + ((size_t)b * TT + c) * DD + c4) = sv;
        }
    }
}

// ---------------------------------------------------------------------------
// k_mlp GEMM: acc[8] = A(fp16 frags in LDS) @ B(fp16 frags in LDS).
// ---------------------------------------------------------------------------
__device__ __forceinline__ void mlp_gemm(f32x4 acc[8], const uint4* Afr4,
    const ushort* Bs, int wv, int l)
{
    half8 af[4];
    #pragma unroll
    for (int kb = 0; kb < 4; ++kb)
        af[kb] = *(const half8*)((const char*)Afr4 + ((wv * 4 + kb) * 64 + l) * 16);
    #pragma unroll
    for (int kb = 0; kb < 4; ++kb) {
        half8 bh[8];
        #pragma unroll
        for (int nt = 0; nt < 8; ++nt)
            bh[nt] = *(const half8*)(Bs + (size_t)((nt * 4 + kb) * 64 + l) * 8);
        #pragma unroll
        for (int nt = 0; nt < 8; ++nt)
            acc[nt] = __builtin_amdgcn_mfma_f32_16x16x32_f16(af[kb], bh[nt], acc[nt], 0, 0, 0);
    }
}

// ---------------------------------------------------------------------------
// Kernel 3b (NEW SPLIT): 3-layer MLP only. Reads fp32 means coalesced from
// cm, packs fp16 A-frags; B0 staged at kernel TOP (its load latency hides
// under the mean loads — impossible in the fused union version). Gate
// written fp32 in-place over cm. No persistent reg arrays (r13 spill lesson).
// ---------------------------------------------------------------------------
__global__ __launch_bounds__(256, 2) void k_mlp3(
    const int* __restrict__ cs,
    const float* __restrict__ ba1, const float* __restrict__ ln_g, const float* __restrict__ ln_b,
    const float* __restrict__ ba2, const float* __restrict__ bd,
    const ushort* __restrict__ wfm, const int* __restrict__ numC, float* __restrict__ cm)
{
    __shared__ struct { uint4 Afr[1024]; uint4 Bs[2048]; } fb;   // 48 KB
    const int b  = blockIdx.y;
    const int nC = numC[b];
    const int c0 = blockIdx.x * 64;
    if (c0 >= nC) return;
    const int tid  = threadIdx.x;
    const int wv   = tid >> 6;
    const int l    = tid & 63;
    const int lo16 = l & 15;
    const int g    = l >> 4;
    const ushort* Bs = (const ushort*)fb.Bs;
    const uint4* wsrc = (const uint4*)wfm;
    (void)cs;

    // stage B layer 0 immediately (overlaps the mean loads below)
    #pragma unroll
    for (int j = 0; j < 8; ++j) { int idx = tid + j * 256; fb.Bs[idx] = wsrc[idx]; }

    // load means (coalesced float4), pack fp16 A-frags
    #pragma unroll
    for (int ii = 0; ii < 8; ++ii) {
        int i = tid + ii * 256;
        int r = i >> 5, c4 = (i & 31) * 4;
        float4 sv = make_float4(0.f, 0.f, 0.f, 0.f);
        if (c0 + r < nC) sv = ld4(cm + ((size_t)b * TT + c0 + r) * DD + c4);
        int frag = (r >> 4) * 4 + (c4 >> 5);
        int lanef = (r & 15) + (((c4 & 31) >> 3) * 16);
        uint2 pk = make_uint2(pk2(sv.x, sv.y), pk2(sv.z, sv.w));
        *(uint2*)((char*)fb.Afr + frag * 1024 + lanef * 16 + (c4 & 7) * 2) = pk;
    }
    __syncthreads();

    // ---- layer 1: h = cm @ Wa1 + ba1; LayerNorm; ReLU ----
    f32x4 acc[8];
    #pragma unroll
    for (int nt = 0; nt < 8; ++nt) {
        float bias = ba1[nt * 16 + lo16];
        acc[nt] = (f32x4){bias, bias, bias, bias};
    }
    mlp_gemm(acc, fb.Afr, Bs, wv, l);

    float mu_[4], rs_[4];
    #pragma unroll
    for (int i = 0; i < 4; ++i) {
        float smv = 0.f;
        #pragma unroll
        for (int nt = 0; nt < 8; ++nt) smv += acc[nt][i];
        #pragma unroll
        for (int k = 1; k < 16; k <<= 1) smv += __shfl_xor(smv, k, 16);
        mu_[i] = smv * (1.f / 128.f);
        float vs = 0.f;
        #pragma unroll
        for (int nt = 0; nt < 8; ++nt) { float d = acc[nt][i] - mu_[i]; vs += d * d; }
        #pragma unroll
        for (int k = 1; k < 16; k <<= 1) vs += __shfl_xor(vs, k, 16);
        rs_[i] = rsqrtf(vs * (1.f / 128.f) + 1e-5f);
    }
    float gam[8], bet[8];
    #pragma unroll
    for (int nt = 0; nt < 8; ++nt) { gam[nt] = ln_g[nt * 16 + lo16]; bet[nt] = ln_b[nt * 16 + lo16]; }

    __syncthreads();   // layer-1 A/B reads done
    #pragma unroll
    for (int nt = 0; nt < 8; ++nt) {
        int cw = nt * 16 + lo16;
        int frag = wv * 4 + (cw >> 5);
        int lnf  = (((cw & 31) >> 3) * 16);
        #pragma unroll
        for (int i = 0; i < 4; ++i) {
            float h = fmaf((acc[nt][i] - mu_[i]) * rs_[i], gam[nt], bet[nt]);
            union { _Float16 f; ushort u; } cv; cv.f = (_Float16)fmaxf(h, 0.f);
            *((ushort*)((char*)fb.Afr + frag * 1024 + ((g * 4 + i) + lnf) * 16 + (cw & 7) * 2)) = cv.u;
        }
    }
    #pragma unroll
    for (int j = 0; j < 8; ++j) { int idx = tid + j * 256; fb.Bs[idx] = wsrc[2048 + idx]; }
    __syncthreads();

    // ---- layer 2: agg = relu(h) @ Wa2 + ba2 ----
    #pragma unroll
    for (int nt = 0; nt < 8; ++nt) {
        float bias = ba2[nt * 16 + lo16];
        acc[nt] = (f32x4){bias, bias, bias, bias};
    }
    mlp_gemm(acc, fb.Afr, Bs, wv, l);
    __syncthreads();   // layer-2 A/B reads done
    #pragma unroll
    for (int nt = 0; nt < 8; ++nt) {
        int cw = nt * 16 + lo16;
        int frag = wv * 4 + (cw >> 5);
        int lnf  = (((cw & 31) >> 3) * 16);
        #pragma unroll
        for (int i = 0; i < 4; ++i) {
            union { _Float16 f; ushort u; } cv; cv.f = (_Float16)acc[nt][i];
            *((ushort*)((char*)fb.Afr + frag * 1024 + ((g * 4 + i) + lnf) * 16 + (cw & 7) * 2)) = cv.u;
        }
    }
    #pragma unroll
    for (int j = 0; j < 8; ++j) { int idx = tid + j * 256; fb.Bs[idx] = wsrc[4096 + idx]; }
    __syncthreads();

    // ---- layer 3: infl = agg @ Wd + bd; gate = sigmoid -> cm (fp32) ----
    #pragma unroll
    for (int nt = 0; nt < 8; ++nt) {
        float bias = bd[nt * 16 + lo16];
        acc[nt] = (f32x4){bias, bias, bias, bias};
    }
    mlp_gemm(acc, fb.Afr, Bs, wv, l);
    #pragma unroll
    for (int i = 0; i < 4; ++i) {
        int row = c0 + wv * 16 + g * 4 + i;
        if (row < nC) {
            float* dst = cm + ((size_t)b * TT + row) * DD + lo16;
            #pragma unroll
            for (int nt = 0; nt < 8; ++nt)
                dst[nt * 16] = 1.f / (1.f + __expf(-acc[nt][i]));
        }
    }
}

// ---------------------------------------------------------------------------
// Kernel 4: out[t] = fma(x[t], gate[seg[t]], x[t])  (round-10 version)
// ---------------------------------------------------------------------------
__global__ __launch_bounds__(256) void k_out(const float* __restrict__ x,
    const int* __restrict__ seg, const float* __restrict__ gate, float* __restrict__ out)
{
    const size_t idx = (size_t)blockIdx.x * 256 + threadIdx.x;
    const size_t tok = idx >> 5;
    const int d4 = (int)(idx & 31);
    const int b  = (int)(tok >> 14);
    const int sg = seg[tok];
    float4 gv = ld4(gate + (((size_t)b << 14) + sg) * DD + d4 * 4);
    float4 xv = ld4(x + tok * DD + (size_t)d4 * 4);
    float4 o;
    o.x = fmaf(xv.x, gv.x, xv.x);
    o.y = fmaf(xv.y, gv.y, xv.y);
    o.z = fmaf(xv.z, gv.z, xv.z);
    o.w = fmaf(xv.w, gv.w, xv.w);
    *(float4*)(out + idx * 4) = o;
}

extern "C" void kernel_launch(void* const* d_in, const int* in_sizes, int n_in,
                              void* d_out, int out_size, void* d_ws, size_t ws_size,
                              hipStream_t stream)
{
    (void)in_sizes; (void)n_in; (void)out_size; (void)ws_size;
    const float* x    = (const float*)d_in[0];
    const float* Wk   = (const float*)d_in[1];
    const float* bk   = (const float*)d_in[2];
    const float* Wq   = (const float*)d_in[3];
    const float* bq   = (const float*)d_in[4];
    const float* Wa1  = (const float*)d_in[5];
    const float* ba1  = (const float*)d_in[6];
    const float* ln_g = (const float*)d_in[7];
    const float* ln_b = (const float*)d_in[8];
    const float* Wa2  = (const float*)d_in[9];
    const float* ba2  = (const float*)d_in[10];
    const float* Wd   = (const float*)d_in[11];
    const float* bd   = (const float*)d_in[12];
    float* out = (float*)d_out;

    // ws layout
    char* p = (char*)d_ws;
    float* cm    = (float*)p;   p += (size_t)BB * TT * DD * 4;   // 64 MB (means -> gate)
    int* seg     = (int*)p;     p += (size_t)BB * TT * 4;        // bind bits -> seg ids
    int* cs      = (int*)p;     p += (size_t)BB * (TT + 1) * 4;
    int* numC    = (int*)p;     p += 64;
    ushort* wfm  = (ushort*)p;  p += 3 * DD * DD * 2;            // MLP W frags fp16 (96 KB)
    ushort* wfb  = (ushort*)p;  p += DD * DD * 2;                // bind W frags fp16 (32 KB)
    int* flist   = (int*)p;     p += (size_t)FCAP * 4;           // fixup list (128 KB)
    int* fcnt    = (int*)p;

    k_wprep<<<dim3(32, 4), 64, 0, stream>>>(Wa1, Wa2, Wd, Wk, Wq, wfm, wfb, fcnt);
    k_bind<<<dim3(256, BB), 256, 0, stream>>>(x, wfb, bk, bq, seg, flist, fcnt);
    k_fixup<<<dim3(256), 256, 0, stream>>>(x, Wk, bk, Wq, bq, flist, fcnt, seg);
    k_scan<<<dim3(BB), 1024, 0, stream>>>(seg, seg, cs, numC);
    k_meanp<<<dim3(TT / 64, BB), 256, 0, stream>>>(x, cs, numC, cm);
    k_mlp3<<<dim3(TT / 64, BB), 256, 0, stream>>>(cs, ba1, ln_g, ln_b, ba2, bd, wfm, numC, cm);
    k_out<<<dim3(BB * TT * DD / (256 * 4)), 256, 0, stream>>>(x, seg, cm, out);
}

// Round 15
// 113.878 us; speedup vs baseline: 1.3598x; 1.0969x over previous
//
#include <hip/hip_runtime.h>
#include <math.h>

#define BB 8
#define TT 16384
#define DD 128
#define DH 64
#define FCAP 32768
#define FMARGIN 0.05f

typedef _Float16 half8 __attribute__((ext_vector_type(8)));
typedef float f32x4 __attribute__((ext_vector_type(4)));

union H8 { half8 h; uint4 q; ushort us[8]; };

static __device__ __forceinline__ float4 ld4(const float* p) { return *(const float4*)p; }

// pack two floats as adjacent fp16 in a u32 (low = first)
static __device__ __forceinline__ uint pk2(float a, float b) {
    union { _Float16 f; ushort u; } A, B;
    A.f = (_Float16)a; B.f = (_Float16)b;
    return (uint)A.u | ((uint)B.u << 16);
}

// split 8 fp32 -> fp16 hi + fp16 lo (x = hi + lo exact to ~2^-22)
static __device__ __forceinline__ void split8h(const float4 v0, const float4 v1,
                                               half8* xh, half8* xl)
{
    float f[8] = {v0.x, v0.y, v0.z, v0.w, v1.x, v1.y, v1.z, v1.w};
    half8 h, l;
    #pragma unroll
    for (int j = 0; j < 8; ++j) {
        _Float16 hv = (_Float16)f[j];
        h[j] = hv;
        l[j] = (_Float16)(f[j] - (float)hv);
    }
    *xh = h; *xl = l;
}

// ---------------------------------------------------------------------------
// Kernel W-prep: weights fp32 -> fp16 MFMA B-fragment layout (single fp16).
// ---------------------------------------------------------------------------
__global__ __launch_bounds__(64) void k_wprep(
    const float* __restrict__ Wa1, const float* __restrict__ Wa2,
    const float* __restrict__ Wd, const float* __restrict__ Wk,
    const float* __restrict__ Wq, ushort* __restrict__ wfm,
    ushort* __restrict__ wfb, int* __restrict__ fcnt)
{
    const int l  = threadIdx.x;
    const int nt = blockIdx.x & 7;
    const int kb = blockIdx.x >> 3;
    const int ly = blockIdx.y;
    if (ly == 0 && blockIdx.x == 0 && l == 0) *fcnt = 0;
    const int n  = nt * 16 + (l & 15);
    const int k0 = kb * 32 + (l >> 4) * 8;
    H8 v;
    if (ly < 3) {
        const float* W = (ly == 0) ? Wa1 : (ly == 1) ? Wa2 : Wd;
        #pragma unroll
        for (int e = 0; e < 8; ++e) v.h[e] = (_Float16)W[(k0 + e) * DD + n];
        *(uint4*)(wfm + (size_t)(((ly * 8 + nt) * 4 + kb) * 64 + l) * 8) = v.q;
    } else {
        #pragma unroll
        for (int e = 0; e < 8; ++e) {
            float w = (n < 64) ? Wk[(k0 + e) * DH + n] : Wq[(k0 + e) * DH + n - 64];
            v.h[e] = (_Float16)w;
        }
        *(uint4*)(wfb + (size_t)((nt * 4 + kb) * 64 + l) * 8) = v.q;
    }
}

// ---------------------------------------------------------------------------
// Kernel 1: binding logits via fp16 MFMA, 2-product. (round-8/10 version)
// ---------------------------------------------------------------------------
__global__ __launch_bounds__(256, 2) void k_bind(
    const float* __restrict__ x, const ushort* __restrict__ wfb,
    const float* __restrict__ bk, const float* __restrict__ bq,
    int* __restrict__ cstart, int* __restrict__ flist, int* __restrict__ fcnt)
{
    __shared__ uint4 Bs4[2048];
    __shared__ float bnd[4][64];
    const int b    = blockIdx.y;
    const int tb   = blockIdx.x * 64;
    const int tid  = threadIdx.x;
    const int wv   = tid >> 6;
    const int l    = tid & 63;
    const int lo16 = l & 15;
    const int g    = l >> 4;

    {
        const uint4* wsrc = (const uint4*)wfb;
        #pragma unroll
        for (int j = 0; j < 8; ++j) { int idx = tid + j * 256; Bs4[idx] = wsrc[idx]; }
    }

    const float* xrow = x + ((size_t)b * TT + tb + wv * 16 + lo16) * DD;
    half8 xh[4], xl[4];
    #pragma unroll
    for (int kb = 0; kb < 4; ++kb) {
        float4 v0 = ld4(xrow + kb * 32 + g * 8);
        float4 v1 = ld4(xrow + kb * 32 + g * 8 + 4);
        split8h(v0, v1, &xh[kb], &xl[kb]);
    }
    int r64 = tb + 64; if (r64 > TT - 1) r64 = TT - 1;
    const float* xq = x + ((size_t)b * TT + r64) * DD;
    half8 qh[4], ql[4];
    H8 z; z.q.x = z.q.y = z.q.z = z.q.w = 0u;
    #pragma unroll
    for (int kb = 0; kb < 4; ++kb) {
        qh[kb] = z.h; ql[kb] = z.h;
        if (lo16 == 0) {
            float4 v0 = ld4(xq + kb * 32 + g * 8);
            float4 v1 = ld4(xq + kb * 32 + g * 8 + 4);
            split8h(v0, v1, &qh[kb], &ql[kb]);
        }
    }

    f32x4 acc[8];
    #pragma unroll
    for (int nt = 0; nt < 8; ++nt) {
        int col = nt * 16 + lo16;
        float bias = (col < 64) ? bk[col] : bq[col - 64];
        acc[nt] = (f32x4){bias, bias, bias, bias};
    }
    f32x4 acc4;
    {
        float bias = bq[wv * 16 + lo16];
        acc4 = (f32x4){bias, bias, bias, bias};
    }

    __syncthreads();
    const ushort* Bs = (const ushort*)Bs4;
    const ushort* Bs_halo = Bs + (size_t)((4 + wv) * 4 * 64 + l) * 8;
    #pragma unroll
    for (int kb = 0; kb < 4; ++kb) {
        half8 bh[8];
        #pragma unroll
        for (int nt = 0; nt < 8; ++nt)
            bh[nt] = *(const half8*)(Bs + (size_t)((nt * 4 + kb) * 64 + l) * 8);
        #pragma unroll
        for (int nt = 0; nt < 8; ++nt) {
            acc[nt] = __builtin_amdgcn_mfma_f32_16x16x32_f16(xh[kb], bh[nt], acc[nt], 0, 0, 0);
            acc[nt] = __builtin_amdgcn_mfma_f32_16x16x32_f16(xl[kb], bh[nt], acc[nt], 0, 0, 0);
        }
        half8 bh4 = *(const half8*)(Bs_halo + (size_t)kb * 64 * 8);
        acc4 = __builtin_amdgcn_mfma_f32_16x16x32_f16(qh[kb], bh4, acc4, 0, 0, 0);
        acc4 = __builtin_amdgcn_mfma_f32_16x16x32_f16(ql[kb], bh4, acc4, 0, 0, 0);
    }

    if (l < 16) {
        if (wv > 0) {
            #pragma unroll
            for (int nt = 0; nt < 4; ++nt) bnd[wv - 1][nt * 16 + lo16] = acc[4 + nt][0];
        }
        bnd[3][wv * 16 + lo16] = acc4[0];
    }
    __syncthreads();

    float qn3[4];
    #pragma unroll
    for (int nt = 0; nt < 4; ++nt) qn3[nt] = __shfl_down(acc[4 + nt][0], 16);
    if (g == 3) {
        #pragma unroll
        for (int nt = 0; nt < 4; ++nt) qn3[nt] = bnd[wv][nt * 16 + lo16];
    }
    float s[4];
    #pragma unroll
    for (int i = 0; i < 3; ++i) {
        float t = 0.f;
        #pragma unroll
        for (int nt = 0; nt < 4; ++nt) t += acc[nt][i] * acc[4 + nt][i + 1];
        s[i] = t;
    }
    {
        float t = 0.f;
        #pragma unroll
        for (int nt = 0; nt < 4; ++nt) t += acc[nt][3] * qn3[nt];
        s[3] = t;
    }
    #pragma unroll
    for (int i = 0; i < 4; ++i) {
        #pragma unroll
        for (int m = 1; m < 16; m <<= 1) s[i] += __shfl_xor(s[i], m);
    }
    if (lo16 == 0) {
        #pragma unroll
        for (int i = 0; i < 4; ++i) {
            int t = tb + wv * 16 + g * 4 + i;
            if (t <= TT - 2) {
                cstart[b * TT + t + 1] = (s[i] > 0.f) ? 0 : 1;
                if (fabsf(s[i]) < FMARGIN) {
                    int pos = atomicAdd(fcnt, 1);
                    if (pos < FCAP) flist[pos] = b * TT + t;
                }
            }
        }
    }
    if (blockIdx.x == 0 && tid == 0) cstart[b * TT] = 1;
}

// ---------------------------------------------------------------------------
// Kernel 1b: exact fp32 recompute of flagged borderline bind decisions.
// ---------------------------------------------------------------------------
__global__ __launch_bounds__(256) void k_fixup(
    const float* __restrict__ x, const float* __restrict__ Wk, const float* __restrict__ bk,
    const float* __restrict__ Wq, const float* __restrict__ bq,
    const int* __restrict__ flist, const int* __restrict__ fcnt, int* __restrict__ cstart)
{
    const int n    = min(*fcnt, FCAP);
    const int wv   = (blockIdx.x * 256 + threadIdx.x) >> 6;
    const int lane = threadIdx.x & 63;
    const int nwv  = gridDim.x * 4;
    for (int i = wv; i < n; i += nwv) {
        int idx = flist[i];
        int b = idx >> 14;
        int t = idx & (TT - 1);
        const float* xt = x + ((size_t)b * TT + t) * DD;
        float K = bk[lane], Q = bq[lane];
        #pragma unroll 8
        for (int k = 0; k < DD; ++k) {
            K = fmaf(xt[k],      Wk[k * DH + lane], K);
            Q = fmaf(xt[DD + k], Wq[k * DH + lane], Q);
        }
        float p = K * Q;
        #pragma unroll
        for (int m = 1; m < 64; m <<= 1) p += __shfl_xor(p, m);
        if (lane == 0) cstart[b * TT + t + 1] = (p > 0.f) ? 0 : 1;
    }
}

// ---------------------------------------------------------------------------
// Kernel 2: per-batch scan -> seg, chunk-start table, counts. (unchanged)
// ---------------------------------------------------------------------------
__global__ __launch_bounds__(1024) void k_scan(const int* __restrict__ cstart,
    int* __restrict__ seg, int* __restrict__ cs, int* __restrict__ numC)
{
    __shared__ int wsum[16];
    const int b = blockIdx.x, tid = threadIdx.x;
    const int wv = tid >> 6, lane = tid & 63;
    const int base = b * TT + tid * 16;
    int v[16];
    #pragma unroll
    for (int i = 0; i < 4; ++i) {
        int4 q = *(const int4*)(cstart + base + i * 4);
        v[i * 4 + 0] = q.x; v[i * 4 + 1] = q.y; v[i * 4 + 2] = q.z; v[i * 4 + 3] = q.w;
    }
    int s[16]; int run = 0;
    #pragma unroll
    for (int i = 0; i < 16; ++i) { run += v[i]; s[i] = run; }
    int incl = run;
    #pragma unroll
    for (int off = 1; off < 64; off <<= 1) {
        int t = __shfl_up(incl, off);
        if (lane >= off) incl += t;
    }
    if (lane == 63) wsum[wv] = incl;
    __syncthreads();
    if (tid < 16) {
        int w = wsum[tid];
        #pragma unroll
        for (int off = 1; off < 16; off <<= 1) {
            int t = __shfl_up(w, off, 16);
            if (tid >= off) w += t;
        }
        wsum[tid] = w;
    }
    __syncthreads();
    const int excl = (wv ? wsum[wv - 1] : 0) + incl - run;
    #pragma unroll
    for (int i = 0; i < 16; ++i) {
        int sg = excl + s[i] - 1;
        seg[base + i] = sg;
        if (v[i]) cs[b * (TT + 1) + sg] = tid * 16 + i;
    }
    if (tid == 1023) {
        int tot = excl + run;
        numC[b] = tot;
        cs[b * (TT + 1) + tot] = TT;
    }
}

// ---------------------------------------------------------------------------
// k_mlp GEMM: acc[8] = A(fp16 frags in LDS) @ B(fp16 frags in LDS).
// ---------------------------------------------------------------------------
__device__ __forceinline__ void mlp_gemm(f32x4 acc[8], const uint4* Afr4,
    const ushort* Bs, int wv, int l)
{
    half8 af[4];
    #pragma unroll
    for (int kb = 0; kb < 4; ++kb)
        af[kb] = *(const half8*)((const char*)Afr4 + ((wv * 4 + kb) * 64 + l) * 16);
    #pragma unroll
    for (int kb = 0; kb < 4; ++kb) {
        half8 bh[8];
        #pragma unroll
        for (int nt = 0; nt < 8; ++nt)
            bh[nt] = *(const half8*)(Bs + (size_t)((nt * 4 + kb) * 64 + l) * 8);
        #pragma unroll
        for (int nt = 0; nt < 8; ++nt)
            acc[nt] = __builtin_amdgcn_mfma_f32_16x16x32_f16(af[kb], bh[nt], acc[nt], 0, 0, 0);
    }
}

// ---------------------------------------------------------------------------
// Kernel 3: per-chunk MLP via fp16 MFMA (round-10 fused structure, 43.5us
// baseline). ONLY CHANGE: phase 1 uses ASYNC global_load_lds double-buffered
// 32-token tiles (zero VGPRs in flight — r13's register dbuf spilled).
// The block's token range [T0,T1) is a CONTIGUOUS slab of x, so the DMA's
// wave-uniform-base + lane*16 constraint is satisfied with an UNPADDED
// Tok[2][32*128] (padding breaks global_load_lds, guide m104). Pipeline:
// vmcnt(0)+barrier -> issue next tile DMA -> reduce current from LDS.
// ---------------------------------------------------------------------------
__global__ __launch_bounds__(256, 2) void k_mlp(
    const float* __restrict__ x, const int* __restrict__ cs,
    const float* __restrict__ ba1, const float* __restrict__ ln_g, const float* __restrict__ ln_b,
    const float* __restrict__ ba2, const float* __restrict__ bd,
    const ushort* __restrict__ wfm, const int* __restrict__ numC, float* __restrict__ cm)
{
    __shared__ union {
        float Tok[2][32 * 128];                            // 2 x 16384 B (UNPADDED: DMA dest)
        struct { uint4 Afr[1024]; uint4 Bs[2048]; } fb;    // 49152 B frags
    } sm;
    const int b  = blockIdx.y;
    const int nC = numC[b];
    const int c0 = blockIdx.x * 64;
    if (c0 >= nC) return;
    const int tid  = threadIdx.x;
    const int wv   = tid >> 6;
    const int l    = tid & 63;
    const int lo16 = l & 15;
    const int g    = l >> 4;
    const ushort* Bs = (const ushort*)sm.fb.Bs;
    const uint4* wsrc = (const uint4*)wfm;

    // ---- phase 1: chunk means, async double-buffered 32-token tiles ----
    const int cbase = b * (TT + 1);
    const int T0 = cs[cbase + c0];
    const int cEnd = (c0 + 64 < nC) ? (c0 + 64) : nC;
    const int T1 = cs[cbase + cEnd];
    int t0r[8], t1r[8];
    #pragma unroll
    for (int ii = 0; ii < 8; ++ii) {
        int r = (tid + ii * 256) >> 5;
        int c = c0 + r;
        t0r[ii] = (c < nC) ? cs[cbase + c] : 0;
        t1r[ii] = (c < nC) ? cs[cbase + c + 1] : 0;
    }
    float4 vals[8];
    #pragma unroll
    for (int ii = 0; ii < 8; ++ii) vals[ii] = make_float4(0.f, 0.f, 0.f, 0.f);

    // prologue: async-stage tile 0 into Tok[0] (16B/lane, wave-uniform dest base)
    {
        const int n16 = ((T0 + 32 < T1) ? 32 : (T1 - T0)) * 32;   // 16B chunks in tile
        #pragma unroll
        for (int j = 0; j < 4; ++j) {
            int base16 = j * 256 + wv * 64;
            if (base16 + l < n16) {
                const float* gs = x + ((size_t)b * TT + T0) * DD + (size_t)(base16 + l) * 4;
                __builtin_amdgcn_global_load_lds(
                    (const __attribute__((address_space(1))) void*)gs,
                    (__attribute__((address_space(3))) void*)&sm.Tok[0][base16 * 4],
                    16, 0, 0);
            }
        }
    }
    int buf = 0;
    for (int tt = T0; tt < T1; tt += 32) {
        asm volatile("s_waitcnt vmcnt(0)" ::: "memory");   // tile[buf] DMA complete
        __syncthreads();
        const int tEnd = (tt + 32 < T1) ? (tt + 32) : T1;
        // issue next tile's DMA into Tok[buf^1] (overlaps the reduce below)
        if (tt + 32 < T1) {
            const int nEnd = (tt + 64 < T1) ? (tt + 64) : T1;
            const int n16 = (nEnd - (tt + 32)) * 32;
            #pragma unroll
            for (int j = 0; j < 4; ++j) {
                int base16 = j * 256 + wv * 64;
                if (base16 + l < n16) {
                    const float* gs = x + ((size_t)b * TT + tt + 32) * DD + (size_t)(base16 + l) * 4;
                    __builtin_amdgcn_global_load_lds(
                        (const __attribute__((address_space(1))) void*)gs,
                        (__attribute__((address_space(3))) void*)&sm.Tok[buf ^ 1][base16 * 4],
                        16, 0, 0);
                }
            }
        }
        // reduce current tile from Tok[buf]
        #pragma unroll
        for (int ii = 0; ii < 8; ++ii) {
            int c4 = ((tid + ii * 256) & 31) * 4;
            int lo = (t0r[ii] > tt)   ? t0r[ii] : tt;
            int hi = (t1r[ii] < tEnd) ? t1r[ii] : tEnd;
            for (int t = lo; t < hi; ++t) {
                const float* ap = &sm.Tok[buf][(t - tt) * 128 + c4];
                vals[ii].x += ap[0]; vals[ii].y += ap[1];
                vals[ii].z += ap[2]; vals[ii].w += ap[3];
            }
        }
        buf ^= 1;
    }
    asm volatile("s_waitcnt vmcnt(0)" ::: "memory");
    __syncthreads();                           // Tok dies; union flips to frags

    // divide means, pack fp16 A-frags; stage B layer 0
    #pragma unroll
    for (int ii = 0; ii < 8; ++ii) {
        int i = tid + ii * 256;
        int r = i >> 5, c4 = (i & 31) * 4;
        float4 sv = make_float4(0.f, 0.f, 0.f, 0.f);
        if (c0 + r < nC) {
            float inv = 1.f / (float)(t1r[ii] - t0r[ii]);
            sv.x = vals[ii].x * inv; sv.y = vals[ii].y * inv;
            sv.z = vals[ii].z * inv; sv.w = vals[ii].w * inv;
        }
        int frag = (r >> 4) * 4 + (c4 >> 5);
        int lanef = (r & 15) + (((c4 & 31) >> 3) * 16);
        uint2 pk = make_uint2(pk2(sv.x, sv.y), pk2(sv.z, sv.w));
        *(uint2*)((char*)sm.fb.Afr + frag * 1024 + lanef * 16 + (c4 & 7) * 2) = pk;
    }
    #pragma unroll
    for (int j = 0; j < 8; ++j) { int idx = tid + j * 256; sm.fb.Bs[idx] = wsrc[idx]; }
    __syncthreads();

    // ---- layer 1: h = cm @ Wa1 + ba1; LayerNorm; ReLU ----
    f32x4 acc[8];
    #pragma unroll
    for (int nt = 0; nt < 8; ++nt) {
        float bias = ba1[nt * 16 + lo16];
        acc[nt] = (f32x4){bias, bias, bias, bias};
    }
    mlp_gemm(acc, sm.fb.Afr, Bs, wv, l);

    float mu_[4], rs_[4];
    #pragma unroll
    for (int i = 0; i < 4; ++i) {
        float smv = 0.f;
        #pragma unroll
        for (int nt = 0; nt < 8; ++nt) smv += acc[nt][i];
        #pragma unroll
        for (int k = 1; k < 16; k <<= 1) smv += __shfl_xor(smv, k, 16);
        mu_[i] = smv * (1.f / 128.f);
        float vs = 0.f;
        #pragma unroll
        for (int nt = 0; nt < 8; ++nt) { float d = acc[nt][i] - mu_[i]; vs += d * d; }
        #pragma unroll
        for (int k = 1; k < 16; k <<= 1) vs += __shfl_xor(vs, k, 16);
        rs_[i] = rsqrtf(vs * (1.f / 128.f) + 1e-5f);
    }
    float gam[8], bet[8];
    #pragma unroll
    for (int nt = 0; nt < 8; ++nt) { gam[nt] = ln_g[nt * 16 + lo16]; bet[nt] = ln_b[nt * 16 + lo16]; }

    __syncthreads();   // layer-1 A/B reads done
    #pragma unroll
    for (int nt = 0; nt < 8; ++nt) {
        int cw = nt * 16 + lo16;
        int frag = wv * 4 + (cw >> 5);
        int lnf  = (((cw & 31) >> 3) * 16);
        #pragma unroll
        for (int i = 0; i < 4; ++i) {
            float h = fmaf((acc[nt][i] - mu_[i]) * rs_[i], gam[nt], bet[nt]);
            union { _Float16 f; ushort u; } cv; cv.f = (_Float16)fmaxf(h, 0.f);
            *((ushort*)((char*)sm.fb.Afr + frag * 1024 + ((g * 4 + i) + lnf) * 16 + (cw & 7) * 2)) = cv.u;
        }
    }
    #pragma unroll
    for (int j = 0; j < 8; ++j) { int idx = tid + j * 256; sm.fb.Bs[idx] = wsrc[2048 + idx]; }
    __syncthreads();

    // ---- layer 2: agg = relu(h) @ Wa2 + ba2 ----
    #pragma unroll
    for (int nt = 0; nt < 8; ++nt) {
        float bias = ba2[nt * 16 + lo16];
        acc[nt] = (f32x4){bias, bias, bias, bias};
    }
    mlp_gemm(acc, sm.fb.Afr, Bs, wv, l);
    __syncthreads();   // layer-2 A/B reads done
    #pragma unroll
    for (int nt = 0; nt < 8; ++nt) {
        int cw = nt * 16 + lo16;
        int frag = wv * 4 + (cw >> 5);
        int lnf  = (((cw & 31) >> 3) * 16);
        #pragma unroll
        for (int i = 0; i < 4; ++i) {
            union { _Float16 f; ushort u; } cv; cv.f = (_Float16)acc[nt][i];
            *((ushort*)((char*)sm.fb.Afr + frag * 1024 + ((g * 4 + i) + lnf) * 16 + (cw & 7) * 2)) = cv.u;
        }
    }
    #pragma unroll
    for (int j = 0; j < 8; ++j) { int idx = tid + j * 256; sm.fb.Bs[idx] = wsrc[4096 + idx]; }
    __syncthreads();

    // ---- layer 3: infl = agg @ Wd + bd; gate = sigmoid -> cm (fp32) ----
    #pragma unroll
    for (int nt = 0; nt < 8; ++nt) {
        float bias = bd[nt * 16 + lo16];
        acc[nt] = (f32x4){bias, bias, bias, bias};
    }
    mlp_gemm(acc, sm.fb.Afr, Bs, wv, l);
    #pragma unroll
    for (int i = 0; i < 4; ++i) {
        int row = c0 + wv * 16 + g * 4 + i;
        if (row < nC) {
            float* dst = cm + ((size_t)b * TT + row) * DD + lo16;
            #pragma unroll
            for (int nt = 0; nt < 8; ++nt)
                dst[nt * 16] = 1.f / (1.f + __expf(-acc[nt][i]));
        }
    }
}

// ---------------------------------------------------------------------------
// Kernel 4: out[t] = fma(x[t], gate[seg[t]], x[t])  (round-10 version)
// ---------------------------------------------------------------------------
__global__ __launch_bounds__(256) void k_out(const float* __restrict__ x,
    const int* __restrict__ seg, const float* __restrict__ gate, float* __restrict__ out)
{
    const size_t idx = (size_t)blockIdx.x * 256 + threadIdx.x;
    const size_t tok = idx >> 5;
    const int d4 = (int)(idx & 31);
    const int b  = (int)(tok >> 14);
    const int sg = seg[tok];
    float4 gv = ld4(gate + (((size_t)b << 14) + sg) * DD + d4 * 4);
    float4 xv = ld4(x + tok * DD + (size_t)d4 * 4);
    float4 o;
    o.x = fmaf(xv.x, gv.x, xv.x);
    o.y = fmaf(xv.y, gv.y, xv.y);
    o.z = fmaf(xv.z, gv.z, xv.z);
    o.w = fmaf(xv.w, gv.w, xv.w);
    *(float4*)(out + idx * 4) = o;
}

extern "C" void kernel_launch(void* const* d_in, const int* in_sizes, int n_in,
                              void* d_out, int out_size, void* d_ws, size_t ws_size,
                              hipStream_t stream)
{
    (void)in_sizes; (void)n_in; (void)out_size; (void)ws_size;
    const float* x    = (const float*)d_in[0];
    const float* Wk   = (const float*)d_in[1];
    const float* bk   = (const float*)d_in[2];
    const float* Wq   = (const float*)d_in[3];
    const float* bq   = (const float*)d_in[4];
    const float* Wa1  = (const float*)d_in[5];
    const float* ba1  = (const float*)d_in[6];
    const float* ln_g = (const float*)d_in[7];
    const float* ln_b = (const float*)d_in[8];
    const float* Wa2  = (const float*)d_in[9];
    const float* ba2  = (const float*)d_in[10];
    const float* Wd   = (const float*)d_in[11];
    const float* bd   = (const float*)d_in[12];
    float* out = (float*)d_out;

    // ws layout
    char* p = (char*)d_ws;
    float* cm    = (float*)p;   p += (size_t)BB * TT * DD * 4;   // 64 MB (means -> gate)
    int* seg     = (int*)p;     p += (size_t)BB * TT * 4;        // bind bits -> seg ids
    int* cs      = (int*)p;     p += (size_t)BB * (TT + 1) * 4;
    int* numC    = (int*)p;     p += 64;
    ushort* wfm  = (ushort*)p;  p += 3 * DD * DD * 2;            // MLP W frags fp16 (96 KB)
    ushort* wfb  = (ushort*)p;  p += DD * DD * 2;                // bind W frags fp16 (32 KB)
    int* flist   = (int*)p;     p += (size_t)FCAP * 4;           // fixup list (128 KB)
    int* fcnt    = (int*)p;

    k_wprep<<<dim3(32, 4), 64, 0, stream>>>(Wa1, Wa2, Wd, Wk, Wq, wfm, wfb, fcnt);
    k_bind<<<dim3(256, BB), 256, 0, stream>>>(x, wfb, bk, bq, seg, flist, fcnt);
    k_fixup<<<dim3(256), 256, 0, stream>>>(x, Wk, bk, Wq, bq, flist, fcnt, seg);
    k_scan<<<dim3(BB), 1024, 0, stream>>>(seg, seg, cs, numC);
    k_mlp<<<dim3(TT / 64, BB), 256, 0, stream>>>(x, cs, ba1, ln_g, ln_b, ba2, bd, wfm, numC, cm);
    k_out<<<dim3(BB * TT * DD / (256 * 4)), 256, 0, stream>>>(x, seg, cm, out);
}